// Round 13
// baseline (326.860 us; speedup 1.0000x reference)
//
#include <hip/hip_runtime.h>
#include <math.h>

#define BB 8
#define LL 8192
#define DD 64
#define HH 128
#define NN 64
#define NLAYER 3
#define LC 64          // chunk length
#define NC 128         // chunks per (b,h) sequence
#define S2S 133        // s2 f32 row stride
#define SIS 136        // sinit16 row stride (halves)

typedef _Float16 half_t;
typedef _Float16 f16x8_t __attribute__((ext_vector_type(8)));
typedef _Float16 f16x4_t __attribute__((ext_vector_type(4)));
typedef _Float16 f16x2_t __attribute__((ext_vector_type(2)));
typedef float    f32x4_t __attribute__((ext_vector_type(4)));

// workspace sizes in float units
#define SZ_WB   ((size_t)HH*NN*2)            // 16384 (per layer)
#define SZ_WGT  ((size_t)NLAYER*256*HH/2)    // 49152 (Wglu f16 [l][g][h])
#define SZ_WO4  ((size_t)32*64*4)            // 8192
#define SZ_WI4  ((size_t)16*128*4)           // 8192
#define SZ_AM   ((size_t)HH*64*192/2)        // 786432  (f16, per layer)
#define SZ_HT   ((size_t)BB*HH*LL/2)         // 4194304 (f16 [b][h][l])
#define SZ_YT   ((size_t)BB*HH*LL/2)         // 4194304 (f16 [b][h][l])
#define SZ_H    ((size_t)BB*LL*HH)           // 8388608 (fp32, last kD only)

// ---------------- weight prep ----------------
__global__ __launch_bounds__(256) void kW1(const float* __restrict__ Wglu,
                                           half_t* __restrict__ wgt) {
  int tid = blockIdx.x*256 + threadIdx.x;        // < 3*256*128/8 = 12288
  const float* src = Wglu + (size_t)tid*8;
  f16x8_t v;
  #pragma unroll
  for (int i = 0; i < 8; i++) v[i] = (half_t)src[i];
  *(f16x8_t*)&wgt[(size_t)tid*8] = v;
}
__global__ __launch_bounds__(256) void kW2(const float* __restrict__ Wout,
                                           float4* __restrict__ wo4) {
  int tid = blockIdx.x*256 + threadIdx.x;        // < 2048
  int h4 = tid >> 6, d = tid & 63;
  wo4[tid] = make_float4(Wout[(4*h4+0)*DD + d], Wout[(4*h4+1)*DD + d],
                         Wout[(4*h4+2)*DD + d], Wout[(4*h4+3)*DD + d]);
}
__global__ __launch_bounds__(256) void kW3(const float* __restrict__ Win,
                                           float4* __restrict__ wip4) {
  int tid = blockIdx.x*256 + threadIdx.x;        // < 2048
  int k4 = tid >> 7, col = tid & 127;
  wip4[tid] = make_float4(Win[(4*k4+0)*HH + col], Win[(4*k4+1)*HH + col],
                          Win[(4*k4+2)*HH + col], Win[(4*k4+3)*HH + col]);
}

// ---------------- kIn: h = x @ W_in + b_in -> f16 [b][h][l] ----------------
__global__ __launch_bounds__(256) void kIn(const float* __restrict__ x,
      const float4* __restrict__ wip4, const float* __restrict__ bin,
      half_t* __restrict__ hT) {
  __shared__ float xs[32][DD];
  size_t row0 = (size_t)blockIdx.x * 32;
  int t = threadIdx.x;
  #pragma unroll
  for (int k = 0; k < 2; k++) {
    int idx = t + k*256;
    int r = idx >> 4, c4 = idx & 15;
    *reinterpret_cast<float4*>(&xs[r][c4*4]) =
        *reinterpret_cast<const float4*>(&x[(row0 + r)*DD + c4*4]);
  }
  __syncthreads();
  int ct = t & 63, rg = t >> 6;
  float acc[8][2];
  float b0 = bin[2*ct], b1 = bin[2*ct+1];
  #pragma unroll
  for (int r = 0; r < 8; r++) { acc[r][0] = b0; acc[r][1] = b1; }
  for (int k4 = 0; k4 < 16; k4++) {
    float4 w0 = wip4[k4*128 + 2*ct];
    float4 w1 = wip4[k4*128 + 2*ct+1];
    #pragma unroll
    for (int r = 0; r < 8; r++) {
      const float4 x4 = *reinterpret_cast<const float4*>(&xs[rg*8 + r][k4*4]);
      acc[r][0] = fmaf(x4.x, w0.x, fmaf(x4.y, w0.y, fmaf(x4.z, w0.z, fmaf(x4.w, w0.w, acc[r][0]))));
      acc[r][1] = fmaf(x4.x, w1.x, fmaf(x4.y, w1.y, fmaf(x4.z, w1.z, fmaf(x4.w, w1.w, acc[r][1]))));
    }
  }
  size_t bb = row0 >> 13;
  int l0 = (int)(row0 & 8191) + rg*8;
  f16x8_t o0, o1;
  #pragma unroll
  for (int r = 0; r < 8; r++) { o0[r] = (half_t)acc[r][0]; o1[r] = (half_t)acc[r][1]; }
  *(f16x8_t*)&hT[((size_t)bb*HH + 2*ct  )*LL + l0] = o0;
  *(f16x8_t*)&hT[((size_t)bb*HH + 2*ct+1)*LL + l0] = o1;
}

// ---------------- kP2: ALL layers' SSM params -> wb3, wl3, Amat3 ----------------
__global__ __launch_bounds__(256) void kP2(const float* __restrict__ logdt,
   const float* __restrict__ logA, const float* __restrict__ Aim,
   const float* __restrict__ Cre, const float* __restrict__ Cim,
   float* __restrict__ wb3, float* __restrict__ wl3, half_t* __restrict__ Amat3) {
  __shared__ float ktap[4][64];
  int layer = blockIdx.x >> 5;
  int blk   = blockIdx.x & 31;
  float* wb = wb3 + (size_t)layer*SZ_WB;
  float* wl = wl3 + (size_t)layer*SZ_WB;
  half_t* Amat = Amat3 + (size_t)layer*HH*64*192;
  int t = threadIdx.x;
  int w = t >> 6;
  int n = t & 63;
  int h = blk*4 + w;
  float dt = expf(logdt[layer*HH + h]);
  int idx = (layer*HH + h)*NN + n;
  float ar = -expf(logA[idx]);
  float ai = Aim[idx];
  float er = expf(dt*ar);
  float wr = er*cosf(dt*ai), wi = er*sinf(dt*ai);   // w = exp(dt*A)
  float inv = 1.f/(ar*ar + ai*ai);
  float mr = wr - 1.f, mi = wi;                     // expm1(dtA)
  float tr = (mr*ar + mi*ai)*inv;                   // expm1(dtA)/A
  float ti = (mi*ar - mr*ai)*inv;
  float c0 = Cre[idx], c1 = Cim[idx];
  float cr = c0*tr - c1*ti, ci = c0*ti + c1*tr;     // C_eff
  wb[(h*NN+n)*2] = wr; wb[(h*NN+n)*2+1] = wi;
  float pr = 1.f, pi = 0.f;                         // w^d
  float qr = cr*wr - ci*wi, qi = cr*wi + ci*wr;     // C~ w^{d+1}
  half_t* Ah = Amat + (size_t)h*64*192;
  for (int d = 0; d < 64; d++) {
    float kd = cr*pr - ci*pi;                       // Re(C~ w^d)
    kd += __shfl_xor(kd, 1);  kd += __shfl_xor(kd, 2);  kd += __shfl_xor(kd, 4);
    kd += __shfl_xor(kd, 8);  kd += __shfl_xor(kd, 16); kd += __shfl_xor(kd, 32);
    if (n == 0) ktap[w][d] = 2.f*kd;
    Ah[(size_t)d*192 + 64 + 2*n]   = (half_t)(2.f*qr);
    Ah[(size_t)d*192 + 64 + 2*n+1] = (half_t)(-2.f*qi);
    float npr = pr*wr - pi*wi, npi = pr*wi + pi*wr; pr = npr; pi = npi;
    float nqr = qr*wr - qi*wi, nqi = qr*wi + qi*wr; qr = nqr; qi = nqi;
  }
  wl[(h*NN+n)*2] = pr; wl[(h*NN+n)*2+1] = pi;       // w^64
  __syncthreads();
  {
    int l = n;
    half_t* row = Ah + (size_t)l*192;
    for (int m = 0; m < 64; m++)
      row[m] = (half_t)((m <= l) ? ktap[w][l - m] : 0.f);
  }
}

// ---------------- kG: FUSED states GEMM + 2-level scan + output GEMM (512 threads) ----------------
// Block = (h,b), 8 waves. Phase 1: S_local = V.U^T (8 waves x 16 MFMA). Phase 2: 2-level scan
// (8 segs x 16 chunks). Phase 3: y = [T|G].[U;Sinit] (8 waves x 24 MFMA).
__global__ __launch_bounds__(512) void kG(const half_t* __restrict__ hT,
      const float* __restrict__ wb, const float* __restrict__ wl,
      const half_t* __restrict__ Amat, half_t* __restrict__ yT) {
  __shared__ half_t va[128*72];          // 18432 B
  __shared__ half_t ub[128*72];          // 18432 B
  __shared__ float  s2[128*S2S];         // 68096 B
  __shared__ half_t sinit16[128*SIS];    // 34816 B
  __shared__ float  segT[8*128];         //  4096 B   (total ~143.9 KB)
  int t = threadIdx.x;
  int h = blockIdx.x >> 3, b = blockIdx.x & 7;
  // ---- phase 0: V build (8 threads per n, 8 powers each) + U stage
  {
    int n = t >> 3, q8 = t & 7;
    float wr = wb[(h*NN+n)*2], wi = wb[(h*NN+n)*2+1];
    float ar = wr, ai = wi;                      // -> w^8
    #pragma unroll
    for (int i = 0; i < 3; i++) { float nr = ar*ar - ai*ai, ni = 2.f*ar*ai; ar = nr; ai = ni; }
    float pr = 1.f, pi = 0.f;
    for (int e = 0; e < 7 - q8; e++) { float nr = pr*ar - pi*ai, ni = pr*ai + pi*ar; pr = nr; pi = ni; }
    int k0 = (7 - q8)*8;
    for (int i = 0; i < 8; i++) {
      int m = 63 - (k0 + i);
      va[(2*n)*72 + m]   = (half_t)pr;           // Re(w^{63-m})
      va[(2*n+1)*72 + m] = (half_t)pi;
      float nr = pr*wr - pi*wi, ni = pr*wi + pi*wr; pr = nr; pi = ni;
    }
  }
  {
    const half_t* src = hT + ((size_t)b*HH + h)*LL;
    #pragma unroll
    for (int i = 0; i < 2; i++) {
      int idx = t + i*512;
      int row = idx >> 3, off = (idx & 7)*8;
      *(f16x8_t*)&ub[row*72 + off] = *(const f16x8_t*)&src[row*64 + off];
    }
  }
  __syncthreads();
  int wid = t >> 6, lane = t & 63;
  int lr = lane & 15, lq = lane >> 4, lk = lq*8;
  // ---- phase 1: local-states GEMM, 8 waves (wr_ = wid&1 M-half, wc = wid>>2.. N-quarter)
  {
    int wr_ = wid & 1, wc = wid >> 1;            // wc 0..3, span 32 cols
    f32x4_t acc[4][2];
    #pragma unroll
    for (int mr = 0; mr < 4; mr++) { acc[mr][0] = (f32x4_t){0.f,0.f,0.f,0.f}; acc[mr][1] = (f32x4_t){0.f,0.f,0.f,0.f}; }
    #pragma unroll
    for (int ks = 0; ks < 2; ks++) {
      int k = ks*32 + lk;
      f16x8_t af[4], bf[2];
      #pragma unroll
      for (int mr = 0; mr < 4; mr++) af[mr] = *(const f16x8_t*)&va[(wr_*64 + mr*16 + lr)*72 + k];
      #pragma unroll
      for (int nc = 0; nc < 2; nc++) bf[nc] = *(const f16x8_t*)&ub[(wc*32 + nc*16 + lr)*72 + k];
      #pragma unroll
      for (int mr = 0; mr < 4; mr++)
        #pragma unroll
        for (int nc = 0; nc < 2; nc++)
          acc[mr][nc] = __builtin_amdgcn_mfma_f32_16x16x32_f16(af[mr], bf[nc], acc[mr][nc], 0, 0, 0);
    }
    #pragma unroll
    for (int mr = 0; mr < 4; mr++)
      #pragma unroll
      for (int nc = 0; nc < 2; nc++)
        #pragma unroll
        for (int r = 0; r < 4; r++)
          s2[(wr_*64 + mr*16 + lq*4 + r)*S2S + (wc*32 + nc*16 + lr)] = acc[mr][nc][r];
  }
  __syncthreads();
  // ---- phase 2: 2-level scan (8 segs x 16 chunks)
  {
    int n = t & 63, seg = t >> 6;
    int c0 = seg*16;
    float w64r = wl[(h*NN+n)*2], w64i = wl[(h*NN+n)*2+1];
    float* pre = &s2[(2*n)*S2S];
    float* pim = &s2[(2*n+1)*S2S];
    float cr = 0.f, ci = 0.f;
    #pragma unroll 4
    for (int i = 0; i < 16; i++) {        // pass 1: local exclusive prefixes
      int c = c0 + i;
      float lre = pre[c], lim = pim[c];
      pre[c] = cr; pim[c] = ci;
      float nr = fmaf(w64r, cr, fmaf(-w64i, ci, lre));
      float ni = fmaf(w64i, cr, fmaf(w64r, ci, lim));
      cr = nr; ci = ni;
    }
    segT[seg*128 + 2*n] = cr; segT[seg*128 + 2*n+1] = ci;
    __syncthreads();
    float ar = w64r, ai = w64i;           // -> w64^16
    #pragma unroll
    for (int i = 0; i < 4; i++) { float nr = ar*ar - ai*ai, ni = 2.f*ar*ai; ar = nr; ai = ni; }
    float br = 0.f, bi = 0.f;             // segment base = scan of segT
    for (int k = 0; k < seg; k++) {
      float tr_ = segT[k*128 + 2*n], ti_ = segT[k*128 + 2*n+1];
      float nr = fmaf(ar, br, fmaf(-ai, bi, tr_));
      float ni = fmaf(ai, br, fmaf(ar, bi, ti_));
      br = nr; bi = ni;
    }
    float wpr = 1.f, wpi = 0.f;           // pass 2: S_c = P_c + w64^{c-c0} * base
    #pragma unroll 4
    for (int i = 0; i < 16; i++) {
      int c = c0 + i;
      float sr = pre[c] + wpr*br - wpi*bi;
      float si = pim[c] + wpr*bi + wpi*br;
      f16x2_t v = { (half_t)sr, (half_t)si };
      *(f16x2_t*)&sinit16[c*SIS + 2*n] = v;
      float nr = wpr*w64r - wpi*w64i, ni = wpr*w64i + wpi*w64r;
      wpr = nr; wpi = ni;
    }
  }
  __syncthreads();
  // ---- phase 3: output GEMM, 8 waves, wave wid owns c-span wid*16
  {
    const half_t* Ag = Amat + (size_t)h*64*192;
    f32x4_t acc[4];
    #pragma unroll
    for (int mr = 0; mr < 4; mr++) acc[mr] = (f32x4_t){0.f,0.f,0.f,0.f};
    int c = wid*16 + lr;
    #pragma unroll
    for (int ks = 0; ks < 6; ks++) {
      int k = ks*32 + lk;
      f16x8_t af[4];
      #pragma unroll
      for (int mr = 0; mr < 4; mr++) af[mr] = *(const f16x8_t*)&Ag[(size_t)(mr*16 + lr)*192 + k];
      f16x8_t bf = (ks < 2) ? *(const f16x8_t*)&ub[c*72 + k]
                            : *(const f16x8_t*)&sinit16[c*SIS + (k - 64)];
      #pragma unroll
      for (int mr = 0; mr < 4; mr++)
        acc[mr] = __builtin_amdgcn_mfma_f32_16x16x32_f16(af[mr], bf, acc[mr], 0, 0, 0);
    }
    half_t* yp = yT + ((size_t)b*HH + h)*LL;
    #pragma unroll
    for (int mr = 0; mr < 4; mr++) {
      int l0 = mr*16 + lq*4;
      f16x4_t v = { (half_t)acc[mr][0], (half_t)acc[mr][1],
                    (half_t)acc[mr][2], (half_t)acc[mr][3] };
      *(f16x4_t*)&yp[c*64 + l0] = v;
    }
  }
}

// ---------------- kD: skip+gelu+MFMA GLU(in-reg gate)+residual+rmsnorm ----------------
// COALESCED mapping: thread t -> h = t>>1, half = t&1, owns 16 consecutive l of one h.
// Lane pairs cover full 64B lines for y/u loads and hT store (was 16B granules at 16KB stride).
// Stage 3/5 column-scalar LDS ops spread across all 32 banks (2 lanes/bank = free).
__global__ __launch_bounds__(256) void kD(const half_t* __restrict__ yT,
     const half_t* __restrict__ hTin, const float* __restrict__ dskip,
     const half_t* __restrict__ wgt, const float* __restrict__ bglu,
     half_t* __restrict__ hT, float* __restrict__ hout, int last) {
  __shared__ half_t ylds[32][136];
  __shared__ float  zlds[32][133];
  __shared__ float  rnorm[32];
  size_t row0 = (size_t)blockIdx.x * 32;
  int b  = (int)(row0 >> 13);
  int l0 = (int)(row0 & 8191);
  int t = threadIdx.x;
  int h  = t >> 1, hf = t & 1;
  int lbase = hf*16;
  // ---- stage 1: 32B contiguous loads; gelu -> ylds column h; u kept in regs
  const half_t* yb = yT   + ((size_t)b*HH + h)*LL + l0 + lbase;
  const half_t* ubp = hTin + ((size_t)b*HH + h)*LL + l0 + lbase;
  f16x8_t ya = *(const f16x8_t*)yb;
  f16x8_t yc = *(const f16x8_t*)(yb + 8);
  f16x8_t ua = *(const f16x8_t*)ubp;
  f16x8_t uc = *(const f16x8_t*)(ubp + 8);
  float d = dskip[h];
  #pragma unroll
  for (int i = 0; i < 8; i++) {
    float v = fmaf((float)ua[i], d, (float)ya[i]);
    float arg = 0.7978845608028654f*(v + 0.044715f*v*v*v);
    arg = fminf(fmaxf(arg, -15.f), 15.f);
    float e = __expf(2.f*arg);
    ylds[lbase + i][h] = (half_t)(0.5f*v*(1.f + (e - 1.f)/(e + 1.f)));
  }
  #pragma unroll
  for (int i = 0; i < 8; i++) {
    float v = fmaf((float)uc[i], d, (float)yc[i]);
    float arg = 0.7978845608028654f*(v + 0.044715f*v*v*v);
    arg = fminf(fmaxf(arg, -15.f), 15.f);
    float e = __expf(2.f*arg);
    ylds[lbase + 8 + i][h] = (half_t)(0.5f*v*(1.f + (e - 1.f)/(e + 1.f)));
  }
  __syncthreads();
  // ---- stage 2: MFMA GLU with in-register gate (unchanged, verified)
  {
    int w = t >> 6, lane = t & 63;
    int lr = lane & 15, lq = lane >> 4;
    f16x8_t af[2][4];
    #pragma unroll
    for (int mt = 0; mt < 2; mt++)
      #pragma unroll
      for (int ks = 0; ks < 4; ks++)
        af[mt][ks] = *(const f16x8_t*)&ylds[mt*16 + lr][ks*32 + lq*8];
    int ntl[4] = { 2*w, 2*w+1, 2*w+8, 2*w+9 };
    f32x4_t acc[2][4];
    #pragma unroll
    for (int mt = 0; mt < 2; mt++)
      #pragma unroll
      for (int p = 0; p < 4; p++) acc[mt][p] = (f32x4_t){0.f,0.f,0.f,0.f};
    #pragma unroll
    for (int p = 0; p < 4; p++) {
      int nt = ntl[p];
      #pragma unroll
      for (int ks = 0; ks < 4; ks++) {
        f16x8_t bf = *(const f16x8_t*)&wgt[(size_t)(nt*16 + lr)*HH + ks*32 + lq*8];
        #pragma unroll
        for (int mt = 0; mt < 2; mt++)
          acc[mt][p] = __builtin_amdgcn_mfma_f32_16x16x32_f16(af[mt][ks], bf, acc[mt][p], 0, 0, 0);
      }
    }
    #pragma unroll
    for (int p = 0; p < 2; p++) {
      int col = 32*w + p*16 + lr;
      float ba = bglu[col], bg = bglu[col + 128];
      #pragma unroll
      for (int mt = 0; mt < 2; mt++)
        #pragma unroll
        for (int r = 0; r < 4; r++) {
          float a = acc[mt][p][r]   + ba;
          float g = acc[mt][p+2][r] + bg;
          float s = 1.f/(1.f + __expf(-g));
          zlds[mt*16 + lq*4 + r][col] = a*s;
        }
    }
  }
  __syncthreads();
  // ---- stage 3: + residual u (own h column; banks spread, 2 lanes/bank)
  #pragma unroll
  for (int i = 0; i < 8; i++) zlds[lbase + i][h]     += (float)ua[i];
  #pragma unroll
  for (int i = 0; i < 8; i++) zlds[lbase + 8 + i][h] += (float)uc[i];
  __syncthreads();
  // ---- stage 4: row 2-norms (flat, conflict-free)
  #pragma unroll
  for (int i = 0; i < 4; i++) {
    int idx = i*256 + t;
    int row = idx >> 5, c4 = idx & 31;
    const float4 f = *reinterpret_cast<const float4*>(&zlds[row][c4*4]);
    float s = fmaf(f.x, f.x, fmaf(f.y, f.y, fmaf(f.z, f.z, f.w*f.w)));
    s += __shfl_xor(s, 1); s += __shfl_xor(s, 2); s += __shfl_xor(s, 4);
    s += __shfl_xor(s, 8); s += __shfl_xor(s, 16);
    if ((t & 31) == 0) rnorm[row] = s;
  }
  __syncthreads();
  // ---- stage 5: scale; coalesced hT store (32B/thread, 64B per h-pair of lanes)
  f16x8_t o0, o1;
  #pragma unroll
  for (int i = 0; i < 8; i++) {
    float sc = 11.313708498984761f / fmaxf(sqrtf(rnorm[lbase + i]), 1e-12f);
    o0[i] = (half_t)(zlds[lbase + i][h]*sc);
  }
  #pragma unroll
  for (int i = 0; i < 8; i++) {
    float sc = 11.313708498984761f / fmaxf(sqrtf(rnorm[lbase + 8 + i]), 1e-12f);
    o1[i] = (half_t)(zlds[lbase + 8 + i][h]*sc);
  }
  half_t* hb = hT + ((size_t)b*HH + h)*LL + l0 + lbase;
  *(f16x8_t*)hb = o0;
  *(f16x8_t*)(hb + 8) = o1;
  // ---- last layer: fp32 hout via flat coalesced pass
  if (last) {
    #pragma unroll
    for (int i = 0; i < 4; i++) {
      int idx = i*256 + t;
      int row = idx >> 5, c4 = idx & 31;
      float sc = 11.313708498984761f / fmaxf(sqrtf(rnorm[row]), 1e-12f);
      float4 f = *reinterpret_cast<const float4*>(&zlds[row][c4*4]);
      f.x *= sc; f.y *= sc; f.z *= sc; f.w *= sc;
      *reinterpret_cast<float4*>(&hout[(row0 + row)*HH + c4*4]) = f;
    }
  }
}

// ---------------- kE: out = h @ W_out + b_out ----------------
__global__ __launch_bounds__(256) void kE(const float* __restrict__ hin,
      const float4* __restrict__ wo4, const float* __restrict__ bout,
      float* __restrict__ out) {
  __shared__ float hs[64][HH];
  size_t row0 = (size_t)blockIdx.x * 64;
  int t = threadIdx.x;
  #pragma unroll
  for (int k = 0; k < 8; k++) {
    int idx = t + k*256;
    int r = idx >> 5, c4 = idx & 31;
    *reinterpret_cast<float4*>(&hs[r][c4*4]) =
        *reinterpret_cast<const float4*>(&hin[(row0 + r)*HH + c4*4]);
  }
  __syncthreads();
  int ct = t & 31, rg = t >> 5;
  float acc[8][2];
  float b0 = bout[2*ct], b1 = bout[2*ct+1];
  #pragma unroll
  for (int r = 0; r < 8; r++) { acc[r][0] = b0; acc[r][1] = b1; }
  for (int h4 = 0; h4 < 32; h4++) {
    float4 w0 = wo4[h4*64 + 2*ct];
    float4 w1 = wo4[h4*64 + 2*ct+1];
    #pragma unroll
    for (int r = 0; r < 8; r++) {
      const float4 h4v = *reinterpret_cast<const float4*>(&hs[rg*8 + r][h4*4]);
      acc[r][0] = fmaf(h4v.x, w0.x, fmaf(h4v.y, w0.y, fmaf(h4v.z, w0.z, fmaf(h4v.w, w0.w, acc[r][0]))));
      acc[r][1] = fmaf(h4v.x, w1.x, fmaf(h4v.y, w1.y, fmaf(h4v.z, w1.z, fmaf(h4v.w, w1.w, acc[r][1]))));
    }
  }
  #pragma unroll
  for (int r = 0; r < 8; r++) {
    float2 v = make_float2(acc[r][0], acc[r][1]);
    *reinterpret_cast<float2*>(&out[(row0 + rg*8 + r)*DD + 2*ct]) = v;
  }
}

extern "C" void kernel_launch(void* const* d_in, const int* in_sizes, int n_in,
                              void* d_out, int out_size, void* d_ws, size_t ws_size,
                              hipStream_t stream) {
  const float* x     = (const float*)d_in[0];
  const float* Win   = (const float*)d_in[1];
  const float* bin   = (const float*)d_in[2];
  const float* logdt = (const float*)d_in[3];
  const float* logA  = (const float*)d_in[4];
  const float* Aim   = (const float*)d_in[5];
  const float* Cre   = (const float*)d_in[6];
  const float* Cim   = (const float*)d_in[7];
  const float* Dsk   = (const float*)d_in[8];
  const float* Wglu  = (const float*)d_in[9];
  const float* bglu  = (const float*)d_in[10];
  const float* Wout  = (const float*)d_in[11];
  const float* bout  = (const float*)d_in[12];
  float* out = (float*)d_out;

  // Total ≈ 77.3 MB (proven-safe < 104.2MB)
  float* ws   = (float*)d_ws;
  float* wb3  = ws;                          // 3*16384
  float* wl3  = wb3 + 3*SZ_WB;               // 3*16384
  float* wgtF = wl3 + 3*SZ_WB;               // 49152
  float* wo4  = wgtF + SZ_WGT;               // 8192
  float* wi4  = wo4 + SZ_WO4;                // 8192
  float* amF  = wi4 + SZ_WI4;                // Amat3 f16: 3*786432 (9.4MB)
  float* htF  = amF + 3*SZ_AM;               // hT f16 (16.8MB)
  float* ytF  = htF + SZ_HT;                 // yT f16 (16.8MB)
  float* hA   = ytF + SZ_YT;                 // fp32 (33.6MB, last layer only)
  half_t* wgt    = (half_t*)wgtF;
  half_t* Amat3  = (half_t*)amF;
  half_t* hT     = (half_t*)htF;
  half_t* yT     = (half_t*)ytF;

  kW1<<<dim3(48), dim3(256), 0, stream>>>(Wglu, wgt);
  kW2<<<dim3(8),  dim3(256), 0, stream>>>(Wout, (float4*)wo4);
  kW3<<<dim3(8),  dim3(256), 0, stream>>>(Win,  (float4*)wi4);
  kP2<<<dim3(96), dim3(256), 0, stream>>>(logdt, logA, Aim, Cre, Cim, wb3, wl3, Amat3);
  kIn<<<dim3(2048), dim3(256), 0, stream>>>(x, (const float4*)wi4, bin, hT);

  for (int layer = 0; layer < NLAYER; ++layer) {
    const float* wb = wb3 + (size_t)layer*SZ_WB;
    const float* wl = wl3 + (size_t)layer*SZ_WB;
    const half_t* Amat = Amat3 + (size_t)layer*HH*64*192;
    kG<<<dim3(1024), dim3(512), 0, stream>>>(hT, wb, wl, Amat, yT);
    kD<<<dim3(2048), dim3(256), 0, stream>>>(yT, hT, Dsk + layer*HH,
                       wgt + (size_t)layer*256*HH,
                       bglu + layer*2*HH, hT, hA, (layer == NLAYER-1) ? 1 : 0);
  }
  kE<<<dim3(1024), dim3(256), 0, stream>>>(hA, (const float4*)wo4, bout, out);
}

// Round 14
// 301.443 us; speedup vs baseline: 1.0843x; 1.0843x over previous
//
#include <hip/hip_runtime.h>
#include <math.h>

#define BB 8
#define LL 8192
#define DD 64
#define HH 128
#define NN 64
#define NLAYER 3
#define LC 64          // chunk length
#define NC 128         // chunks per (b,h) sequence
#define LST 137        // local-sums f16 row stride (odd -> scan reads spread all banks)
#define SIS 136        // sinit f16 [c][n2] row stride (mult of 8 -> aligned f16x8 reads)

typedef _Float16 half_t;
typedef _Float16 f16x8_t __attribute__((ext_vector_type(8)));
typedef _Float16 f16x4_t __attribute__((ext_vector_type(4)));
typedef _Float16 f16x2_t __attribute__((ext_vector_type(2)));
typedef float    f32x4_t __attribute__((ext_vector_type(4)));

// workspace sizes in float units
#define SZ_WB   ((size_t)HH*NN*2)            // 16384 (per layer)
#define SZ_WGT  ((size_t)NLAYER*256*HH/2)    // 49152 (Wglu f16 [l][g][h])
#define SZ_WO4  ((size_t)32*64*4)            // 8192
#define SZ_WI4  ((size_t)16*128*4)           // 8192
#define SZ_AM   ((size_t)HH*64*192/2)        // 786432  (f16, per layer)
#define SZ_HT   ((size_t)BB*HH*LL/2)         // 4194304 (f16 [b][h][l])
#define SZ_YT   ((size_t)BB*HH*LL/2)         // 4194304 (f16 [b][h][l])
#define SZ_H    ((size_t)BB*LL*HH)           // 8388608 (fp32, last kD only)

// ---------------- weight prep ----------------
__global__ __launch_bounds__(256) void kW1(const float* __restrict__ Wglu,
                                           half_t* __restrict__ wgt) {
  int tid = blockIdx.x*256 + threadIdx.x;        // < 3*256*128/8 = 12288
  const float* src = Wglu + (size_t)tid*8;
  f16x8_t v;
  #pragma unroll
  for (int i = 0; i < 8; i++) v[i] = (half_t)src[i];
  *(f16x8_t*)&wgt[(size_t)tid*8] = v;
}
__global__ __launch_bounds__(256) void kW2(const float* __restrict__ Wout,
                                           float4* __restrict__ wo4) {
  int tid = blockIdx.x*256 + threadIdx.x;        // < 2048
  int h4 = tid >> 6, d = tid & 63;
  wo4[tid] = make_float4(Wout[(4*h4+0)*DD + d], Wout[(4*h4+1)*DD + d],
                         Wout[(4*h4+2)*DD + d], Wout[(4*h4+3)*DD + d]);
}
__global__ __launch_bounds__(256) void kW3(const float* __restrict__ Win,
                                           float4* __restrict__ wip4) {
  int tid = blockIdx.x*256 + threadIdx.x;        // < 2048
  int k4 = tid >> 7, col = tid & 127;
  wip4[tid] = make_float4(Win[(4*k4+0)*HH + col], Win[(4*k4+1)*HH + col],
                          Win[(4*k4+2)*HH + col], Win[(4*k4+3)*HH + col]);
}

// ---------------- kIn: h = x @ W_in + b_in -> f16 [b][h][l] ----------------
__global__ __launch_bounds__(256) void kIn(const float* __restrict__ x,
      const float4* __restrict__ wip4, const float* __restrict__ bin,
      half_t* __restrict__ hT) {
  __shared__ float xs[32][DD];
  size_t row0 = (size_t)blockIdx.x * 32;
  int t = threadIdx.x;
  #pragma unroll
  for (int k = 0; k < 2; k++) {
    int idx = t + k*256;
    int r = idx >> 4, c4 = idx & 15;
    *reinterpret_cast<float4*>(&xs[r][c4*4]) =
        *reinterpret_cast<const float4*>(&x[(row0 + r)*DD + c4*4]);
  }
  __syncthreads();
  int ct = t & 63, rg = t >> 6;
  float acc[8][2];
  float b0 = bin[2*ct], b1 = bin[2*ct+1];
  #pragma unroll
  for (int r = 0; r < 8; r++) { acc[r][0] = b0; acc[r][1] = b1; }
  for (int k4 = 0; k4 < 16; k4++) {
    float4 w0 = wip4[k4*128 + 2*ct];
    float4 w1 = wip4[k4*128 + 2*ct+1];
    #pragma unroll
    for (int r = 0; r < 8; r++) {
      const float4 x4 = *reinterpret_cast<const float4*>(&xs[rg*8 + r][k4*4]);
      acc[r][0] = fmaf(x4.x, w0.x, fmaf(x4.y, w0.y, fmaf(x4.z, w0.z, fmaf(x4.w, w0.w, acc[r][0]))));
      acc[r][1] = fmaf(x4.x, w1.x, fmaf(x4.y, w1.y, fmaf(x4.z, w1.z, fmaf(x4.w, w1.w, acc[r][1]))));
    }
  }
  size_t bb = row0 >> 13;
  int l0 = (int)(row0 & 8191) + rg*8;
  f16x8_t o0, o1;
  #pragma unroll
  for (int r = 0; r < 8; r++) { o0[r] = (half_t)acc[r][0]; o1[r] = (half_t)acc[r][1]; }
  *(f16x8_t*)&hT[((size_t)bb*HH + 2*ct  )*LL + l0] = o0;
  *(f16x8_t*)&hT[((size_t)bb*HH + 2*ct+1)*LL + l0] = o1;
}

// ---------------- kP2: ALL layers' SSM params -> wb3, wl3, Amat3 ----------------
__global__ __launch_bounds__(256) void kP2(const float* __restrict__ logdt,
   const float* __restrict__ logA, const float* __restrict__ Aim,
   const float* __restrict__ Cre, const float* __restrict__ Cim,
   float* __restrict__ wb3, float* __restrict__ wl3, half_t* __restrict__ Amat3) {
  __shared__ float ktap[4][64];
  int layer = blockIdx.x >> 5;
  int blk   = blockIdx.x & 31;
  float* wb = wb3 + (size_t)layer*SZ_WB;
  float* wl = wl3 + (size_t)layer*SZ_WB;
  half_t* Amat = Amat3 + (size_t)layer*HH*64*192;
  int t = threadIdx.x;
  int w = t >> 6;
  int n = t & 63;
  int h = blk*4 + w;
  float dt = expf(logdt[layer*HH + h]);
  int idx = (layer*HH + h)*NN + n;
  float ar = -expf(logA[idx]);
  float ai = Aim[idx];
  float er = expf(dt*ar);
  float wr = er*cosf(dt*ai), wi = er*sinf(dt*ai);   // w = exp(dt*A)
  float inv = 1.f/(ar*ar + ai*ai);
  float mr = wr - 1.f, mi = wi;                     // expm1(dtA)
  float tr = (mr*ar + mi*ai)*inv;                   // expm1(dtA)/A
  float ti = (mi*ar - mr*ai)*inv;
  float c0 = Cre[idx], c1 = Cim[idx];
  float cr = c0*tr - c1*ti, ci = c0*ti + c1*tr;     // C_eff
  wb[(h*NN+n)*2] = wr; wb[(h*NN+n)*2+1] = wi;
  float pr = 1.f, pi = 0.f;                         // w^d
  float qr = cr*wr - ci*wi, qi = cr*wi + ci*wr;     // C~ w^{d+1}
  half_t* Ah = Amat + (size_t)h*64*192;
  for (int d = 0; d < 64; d++) {
    float kd = cr*pr - ci*pi;                       // Re(C~ w^d)
    kd += __shfl_xor(kd, 1);  kd += __shfl_xor(kd, 2);  kd += __shfl_xor(kd, 4);
    kd += __shfl_xor(kd, 8);  kd += __shfl_xor(kd, 16); kd += __shfl_xor(kd, 32);
    if (n == 0) ktap[w][d] = 2.f*kd;
    Ah[(size_t)d*192 + 64 + 2*n]   = (half_t)(2.f*qr);
    Ah[(size_t)d*192 + 64 + 2*n+1] = (half_t)(-2.f*qi);
    float npr = pr*wr - pi*wi, npi = pr*wi + pi*wr; pr = npr; pi = npi;
    float nqr = qr*wr - qi*wi, nqi = qr*wi + qi*wr; qr = nqr; qi = nqi;
  }
  wl[(h*NN+n)*2] = pr; wl[(h*NN+n)*2+1] = pi;       // w^64
  __syncthreads();
  {
    int l = n;
    half_t* row = Ah + (size_t)l*192;
    for (int m = 0; m < 64; m++)
      row[m] = (half_t)((m <= l) ? ktap[w][l - m] : 0.f);
  }
}

// ---------------- kG: FUSED states GEMM + scan + output GEMM (512 thr, 76KB LDS = 2 blk/CU) ----------------
// spad dual-use (barrier-separated): phase1/2 = local sums f16 [n2][LST=137] (odd stride ->
// scan reads conflict-free); after scan = sinit f16 [c][SIS=136] (aligned f16x8 phase-3 reads).
// Prefixes held in REGISTERS (preg[16]) -> no P round-trip through LDS.
__global__ __launch_bounds__(512) void kG(const half_t* __restrict__ hT,
      const float* __restrict__ wb, const float* __restrict__ wl,
      const half_t* __restrict__ Amat, half_t* __restrict__ yT) {
  __shared__ half_t va[128*72];          // 18432 B
  __shared__ half_t ub[128*72];          // 18432 B
  __shared__ half_t spad[128*LST];       // 35072 B (>= 128*SIS = 34816)
  __shared__ float  segT[8*128];         //  4096 B   total ~76.2 KB
  int t = threadIdx.x;
  int h = blockIdx.x >> 3, b = blockIdx.x & 7;
  // ---- phase 0: V build (8 threads per n) + U stage
  {
    int n = t >> 3, q8 = t & 7;
    float wr = wb[(h*NN+n)*2], wi = wb[(h*NN+n)*2+1];
    float ar = wr, ai = wi;                      // -> w^8
    #pragma unroll
    for (int i = 0; i < 3; i++) { float nr = ar*ar - ai*ai, ni = 2.f*ar*ai; ar = nr; ai = ni; }
    float pr = 1.f, pi = 0.f;
    for (int e = 0; e < 7 - q8; e++) { float nr = pr*ar - pi*ai, ni = pr*ai + pi*ar; pr = nr; pi = ni; }
    int k0 = (7 - q8)*8;
    for (int i = 0; i < 8; i++) {
      int m = 63 - (k0 + i);
      va[(2*n)*72 + m]   = (half_t)pr;           // Re(w^{63-m})
      va[(2*n+1)*72 + m] = (half_t)pi;
      float nr = pr*wr - pi*wi, ni = pr*wi + pi*wr; pr = nr; pi = ni;
    }
  }
  {
    const half_t* src = hT + ((size_t)b*HH + h)*LL;
    #pragma unroll
    for (int i = 0; i < 2; i++) {
      int idx = t + i*512;
      int row = idx >> 3, off = (idx & 7)*8;
      *(f16x8_t*)&ub[row*72 + off] = *(const f16x8_t*)&src[row*64 + off];
    }
  }
  __syncthreads();
  int wid = t >> 6, lane = t & 63;
  int lr = lane & 15, lq = lane >> 4, lk = lq*8;
  // ---- phase 1: local-states GEMM, 8 waves; store f16 into spad [n2][LST]
  {
    int wr_ = wid & 1, wc = wid >> 1;            // wc 0..3, span 32 cols
    f32x4_t acc[4][2];
    #pragma unroll
    for (int mr = 0; mr < 4; mr++) { acc[mr][0] = (f32x4_t){0.f,0.f,0.f,0.f}; acc[mr][1] = (f32x4_t){0.f,0.f,0.f,0.f}; }
    #pragma unroll
    for (int ks = 0; ks < 2; ks++) {
      int k = ks*32 + lk;
      f16x8_t af[4], bf[2];
      #pragma unroll
      for (int mr = 0; mr < 4; mr++) af[mr] = *(const f16x8_t*)&va[(wr_*64 + mr*16 + lr)*72 + k];
      #pragma unroll
      for (int nc = 0; nc < 2; nc++) bf[nc] = *(const f16x8_t*)&ub[(wc*32 + nc*16 + lr)*72 + k];
      #pragma unroll
      for (int mr = 0; mr < 4; mr++)
        #pragma unroll
        for (int nc = 0; nc < 2; nc++)
          acc[mr][nc] = __builtin_amdgcn_mfma_f32_16x16x32_f16(af[mr], bf[nc], acc[mr][nc], 0, 0, 0);
    }
    #pragma unroll
    for (int mr = 0; mr < 4; mr++)
      #pragma unroll
      for (int nc = 0; nc < 2; nc++)
        #pragma unroll
        for (int r = 0; r < 4; r++)
          spad[(wr_*64 + mr*16 + lq*4 + r)*LST + (wc*32 + nc*16 + lr)] = (half_t)acc[mr][nc][r];
  }
  __syncthreads();
  // ---- phase 2: scan; prefixes in registers; transposed sinit write into spad
  {
    int n = t & 63, seg = t >> 6;
    int c0 = seg*16;
    float w64r = wl[(h*NN+n)*2], w64i = wl[(h*NN+n)*2+1];
    float pregr[16], pregi[16];
    float cr = 0.f, ci = 0.f;
    #pragma unroll
    for (int i = 0; i < 16; i++) {        // pass 1: L reads (f16), prefixes -> regs
      int c = c0 + i;
      float lre = (float)spad[(2*n)*LST + c];
      float lim = (float)spad[(2*n+1)*LST + c];
      pregr[i] = cr; pregi[i] = ci;
      float nr = fmaf(w64r, cr, fmaf(-w64i, ci, lre));
      float ni = fmaf(w64i, cr, fmaf(w64r, ci, lim));
      cr = nr; ci = ni;
    }
    segT[seg*128 + 2*n] = cr; segT[seg*128 + 2*n+1] = ci;
    __syncthreads();                      // also fences all pass-1 spad reads
    float ar = w64r, ai = w64i;           // -> w64^16
    #pragma unroll
    for (int i = 0; i < 4; i++) { float nr = ar*ar - ai*ai, ni = 2.f*ar*ai; ar = nr; ai = ni; }
    float br = 0.f, bi = 0.f;             // segment base = scan of segT
    for (int k = 0; k < seg; k++) {
      float tr_ = segT[k*128 + 2*n], ti_ = segT[k*128 + 2*n+1];
      float nr = fmaf(ar, br, fmaf(-ai, bi, tr_));
      float ni = fmaf(ai, br, fmaf(ar, bi, ti_));
      br = nr; bi = ni;
    }
    float wpr = 1.f, wpi = 0.f;           // pass 2: S_c = preg + w64^i * base -> sinit [c][n2]
    #pragma unroll
    for (int i = 0; i < 16; i++) {
      int c = c0 + i;
      float sr = pregr[i] + wpr*br - wpi*bi;
      float si = pregi[i] + wpr*bi + wpi*br;
      f16x2_t v = { (half_t)sr, (half_t)si };
      *(f16x2_t*)&spad[c*SIS + 2*n] = v;
      float nr = wpr*w64r - wpi*w64i, ni = wpr*w64i + wpi*w64r;
      wpr = nr; wpi = ni;
    }
  }
  __syncthreads();
  // ---- phase 3: output GEMM, 8 waves, wave wid owns c-span wid*16
  {
    const half_t* Ag = Amat + (size_t)h*64*192;
    f32x4_t acc[4];
    #pragma unroll
    for (int mr = 0; mr < 4; mr++) acc[mr] = (f32x4_t){0.f,0.f,0.f,0.f};
    int c = wid*16 + lr;
    #pragma unroll
    for (int ks = 0; ks < 6; ks++) {
      int k = ks*32 + lk;
      f16x8_t af[4];
      #pragma unroll
      for (int mr = 0; mr < 4; mr++) af[mr] = *(const f16x8_t*)&Ag[(size_t)(mr*16 + lr)*192 + k];
      f16x8_t bf = (ks < 2) ? *(const f16x8_t*)&ub[c*72 + k]
                            : *(const f16x8_t*)&spad[c*SIS + (k - 64)];
      #pragma unroll
      for (int mr = 0; mr < 4; mr++)
        acc[mr] = __builtin_amdgcn_mfma_f32_16x16x32_f16(af[mr], bf, acc[mr], 0, 0, 0);
    }
    half_t* yp = yT + ((size_t)b*HH + h)*LL;
    #pragma unroll
    for (int mr = 0; mr < 4; mr++) {
      int l0 = mr*16 + lq*4;
      f16x4_t v = { (half_t)acc[mr][0], (half_t)acc[mr][1],
                    (half_t)acc[mr][2], (half_t)acc[mr][3] };
      *(f16x4_t*)&yp[c*64 + l0] = v;
    }
  }
}

// ---------------- kD: skip+gelu+MFMA GLU(in-reg gate)+residual+rmsnorm ----------------
// Coalesced mapping: thread t -> h = t>>1, half = t&1, 16 consecutive l of one h.
__global__ __launch_bounds__(256) void kD(const half_t* __restrict__ yT,
     const half_t* __restrict__ hTin, const float* __restrict__ dskip,
     const half_t* __restrict__ wgt, const float* __restrict__ bglu,
     half_t* __restrict__ hT, float* __restrict__ hout, int last) {
  __shared__ half_t ylds[32][136];
  __shared__ float  zlds[32][133];
  __shared__ float  rnorm[32];
  size_t row0 = (size_t)blockIdx.x * 32;
  int b  = (int)(row0 >> 13);
  int l0 = (int)(row0 & 8191);
  int t = threadIdx.x;
  int h  = t >> 1, hf = t & 1;
  int lbase = hf*16;
  const half_t* yb = yT   + ((size_t)b*HH + h)*LL + l0 + lbase;
  const half_t* ubp = hTin + ((size_t)b*HH + h)*LL + l0 + lbase;
  f16x8_t ya = *(const f16x8_t*)yb;
  f16x8_t yc = *(const f16x8_t*)(yb + 8);
  f16x8_t ua = *(const f16x8_t*)ubp;
  f16x8_t uc = *(const f16x8_t*)(ubp + 8);
  float d = dskip[h];
  #pragma unroll
  for (int i = 0; i < 8; i++) {
    float v = fmaf((float)ua[i], d, (float)ya[i]);
    float arg = 0.7978845608028654f*(v + 0.044715f*v*v*v);
    arg = fminf(fmaxf(arg, -15.f), 15.f);
    float e = __expf(2.f*arg);
    ylds[lbase + i][h] = (half_t)(0.5f*v*(1.f + (e - 1.f)/(e + 1.f)));
  }
  #pragma unroll
  for (int i = 0; i < 8; i++) {
    float v = fmaf((float)uc[i], d, (float)yc[i]);
    float arg = 0.7978845608028654f*(v + 0.044715f*v*v*v);
    arg = fminf(fmaxf(arg, -15.f), 15.f);
    float e = __expf(2.f*arg);
    ylds[lbase + 8 + i][h] = (half_t)(0.5f*v*(1.f + (e - 1.f)/(e + 1.f)));
  }
  __syncthreads();
  {
    int w = t >> 6, lane = t & 63;
    int lr = lane & 15, lq = lane >> 4;
    f16x8_t af[2][4];
    #pragma unroll
    for (int mt = 0; mt < 2; mt++)
      #pragma unroll
      for (int ks = 0; ks < 4; ks++)
        af[mt][ks] = *(const f16x8_t*)&ylds[mt*16 + lr][ks*32 + lq*8];
    int ntl[4] = { 2*w, 2*w+1, 2*w+8, 2*w+9 };
    f32x4_t acc[2][4];
    #pragma unroll
    for (int mt = 0; mt < 2; mt++)
      #pragma unroll
      for (int p = 0; p < 4; p++) acc[mt][p] = (f32x4_t){0.f,0.f,0.f,0.f};
    #pragma unroll
    for (int p = 0; p < 4; p++) {
      int nt = ntl[p];
      #pragma unroll
      for (int ks = 0; ks < 4; ks++) {
        f16x8_t bf = *(const f16x8_t*)&wgt[(size_t)(nt*16 + lr)*HH + ks*32 + lq*8];
        #pragma unroll
        for (int mt = 0; mt < 2; mt++)
          acc[mt][p] = __builtin_amdgcn_mfma_f32_16x16x32_f16(af[mt][ks], bf, acc[mt][p], 0, 0, 0);
      }
    }
    #pragma unroll
    for (int p = 0; p < 2; p++) {
      int col = 32*w + p*16 + lr;
      float ba = bglu[col], bg = bglu[col + 128];
      #pragma unroll
      for (int mt = 0; mt < 2; mt++)
        #pragma unroll
        for (int r = 0; r < 4; r++) {
          float a = acc[mt][p][r]   + ba;
          float g = acc[mt][p+2][r] + bg;
          float s = 1.f/(1.f + __expf(-g));
          zlds[mt*16 + lq*4 + r][col] = a*s;
        }
    }
  }
  __syncthreads();
  #pragma unroll
  for (int i = 0; i < 8; i++) zlds[lbase + i][h]     += (float)ua[i];
  #pragma unroll
  for (int i = 0; i < 8; i++) zlds[lbase + 8 + i][h] += (float)uc[i];
  __syncthreads();
  #pragma unroll
  for (int i = 0; i < 4; i++) {
    int idx = i*256 + t;
    int row = idx >> 5, c4 = idx & 31;
    const float4 f = *reinterpret_cast<const float4*>(&zlds[row][c4*4]);
    float s = fmaf(f.x, f.x, fmaf(f.y, f.y, fmaf(f.z, f.z, f.w*f.w)));
    s += __shfl_xor(s, 1); s += __shfl_xor(s, 2); s += __shfl_xor(s, 4);
    s += __shfl_xor(s, 8); s += __shfl_xor(s, 16);
    if ((t & 31) == 0) rnorm[row] = s;
  }
  __syncthreads();
  f16x8_t o0, o1;
  #pragma unroll
  for (int i = 0; i < 8; i++) {
    float sc = 11.313708498984761f / fmaxf(sqrtf(rnorm[lbase + i]), 1e-12f);
    o0[i] = (half_t)(zlds[lbase + i][h]*sc);
  }
  #pragma unroll
  for (int i = 0; i < 8; i++) {
    float sc = 11.313708498984761f / fmaxf(sqrtf(rnorm[lbase + 8 + i]), 1e-12f);
    o1[i] = (half_t)(zlds[lbase + 8 + i][h]*sc);
  }
  half_t* hb = hT + ((size_t)b*HH + h)*LL + l0 + lbase;
  *(f16x8_t*)hb = o0;
  *(f16x8_t*)(hb + 8) = o1;
  if (last) {
    #pragma unroll
    for (int i = 0; i < 4; i++) {
      int idx = i*256 + t;
      int row = idx >> 5, c4 = idx & 31;
      float sc = 11.313708498984761f / fmaxf(sqrtf(rnorm[row]), 1e-12f);
      float4 f = *reinterpret_cast<const float4*>(&zlds[row][c4*4]);
      f.x *= sc; f.y *= sc; f.z *= sc; f.w *= sc;
      *reinterpret_cast<float4*>(&hout[(row0 + row)*HH + c4*4]) = f;
    }
  }
}

// ---------------- kE: out = h @ W_out + b_out ----------------
__global__ __launch_bounds__(256) void kE(const float* __restrict__ hin,
      const float4* __restrict__ wo4, const float* __restrict__ bout,
      float* __restrict__ out) {
  __shared__ float hs[64][HH];
  size_t row0 = (size_t)blockIdx.x * 64;
  int t = threadIdx.x;
  #pragma unroll
  for (int k = 0; k < 8; k++) {
    int idx = t + k*256;
    int r = idx >> 5, c4 = idx & 31;
    *reinterpret_cast<float4*>(&hs[r][c4*4]) =
        *reinterpret_cast<const float4*>(&hin[(row0 + r)*HH + c4*4]);
  }
  __syncthreads();
  int ct = t & 31, rg = t >> 5;
  float acc[8][2];
  float b0 = bout[2*ct], b1 = bout[2*ct+1];
  #pragma unroll
  for (int r = 0; r < 8; r++) { acc[r][0] = b0; acc[r][1] = b1; }
  for (int h4 = 0; h4 < 32; h4++) {
    float4 w0 = wo4[h4*64 + 2*ct];
    float4 w1 = wo4[h4*64 + 2*ct+1];
    #pragma unroll
    for (int r = 0; r < 8; r++) {
      const float4 h4v = *reinterpret_cast<const float4*>(&hs[rg*8 + r][h4*4]);
      acc[r][0] = fmaf(h4v.x, w0.x, fmaf(h4v.y, w0.y, fmaf(h4v.z, w0.z, fmaf(h4v.w, w0.w, acc[r][0]))));
      acc[r][1] = fmaf(h4v.x, w1.x, fmaf(h4v.y, w1.y, fmaf(h4v.z, w1.z, fmaf(h4v.w, w1.w, acc[r][1]))));
    }
  }
  #pragma unroll
  for (int r = 0; r < 8; r++) {
    float2 v = make_float2(acc[r][0], acc[r][1]);
    *reinterpret_cast<float2*>(&out[(row0 + rg*8 + r)*DD + 2*ct]) = v;
  }
}

extern "C" void kernel_launch(void* const* d_in, const int* in_sizes, int n_in,
                              void* d_out, int out_size, void* d_ws, size_t ws_size,
                              hipStream_t stream) {
  const float* x     = (const float*)d_in[0];
  const float* Win   = (const float*)d_in[1];
  const float* bin   = (const float*)d_in[2];
  const float* logdt = (const float*)d_in[3];
  const float* logA  = (const float*)d_in[4];
  const float* Aim   = (const float*)d_in[5];
  const float* Cre   = (const float*)d_in[6];
  const float* Cim   = (const float*)d_in[7];
  const float* Dsk   = (const float*)d_in[8];
  const float* Wglu  = (const float*)d_in[9];
  const float* bglu  = (const float*)d_in[10];
  const float* Wout  = (const float*)d_in[11];
  const float* bout  = (const float*)d_in[12];
  float* out = (float*)d_out;

  // Total ≈ 77.3 MB (proven-safe < 104.2MB)
  float* ws   = (float*)d_ws;
  float* wb3  = ws;                          // 3*16384
  float* wl3  = wb3 + 3*SZ_WB;               // 3*16384
  float* wgtF = wl3 + 3*SZ_WB;               // 49152
  float* wo4  = wgtF + SZ_WGT;               // 8192
  float* wi4  = wo4 + SZ_WO4;                // 8192
  float* amF  = wi4 + SZ_WI4;                // Amat3 f16: 3*786432 (9.4MB)
  float* htF  = amF + 3*SZ_AM;               // hT f16 (16.8MB)
  float* ytF  = htF + SZ_HT;                 // yT f16 (16.8MB)
  float* hA   = ytF + SZ_YT;                 // fp32 (33.6MB, last layer only)
  half_t* wgt    = (half_t*)wgtF;
  half_t* Amat3  = (half_t*)amF;
  half_t* hT     = (half_t*)htF;
  half_t* yT     = (half_t*)ytF;

  kW1<<<dim3(48), dim3(256), 0, stream>>>(Wglu, wgt);
  kW2<<<dim3(8),  dim3(256), 0, stream>>>(Wout, (float4*)wo4);
  kW3<<<dim3(8),  dim3(256), 0, stream>>>(Win,  (float4*)wi4);
  kP2<<<dim3(96), dim3(256), 0, stream>>>(logdt, logA, Aim, Cre, Cim, wb3, wl3, Amat3);
  kIn<<<dim3(2048), dim3(256), 0, stream>>>(x, (const float4*)wi4, bin, hT);

  for (int layer = 0; layer < NLAYER; ++layer) {
    const float* wb = wb3 + (size_t)layer*SZ_WB;
    const float* wl = wl3 + (size_t)layer*SZ_WB;
    const half_t* Amat = Amat3 + (size_t)layer*HH*64*192;
    kG<<<dim3(1024), dim3(512), 0, stream>>>(hT, wb, wl, Amat, yT);
    kD<<<dim3(2048), dim3(256), 0, stream>>>(yT, hT, Dsk + layer*HH,
                       wgt + (size_t)layer*256*HH,
                       bglu + layer*2*HH, hT, hA, (layer == NLAYER-1) ? 1 : 0);
  }
  kE<<<dim3(1024), dim3(256), 0, stream>>>(hA, (const float4*)wo4, bout, out);
}

// Round 15
// 267.591 us; speedup vs baseline: 1.2215x; 1.1265x over previous
//
#include <hip/hip_runtime.h>
#include <math.h>

#define BB 8
#define LL 8192
#define DD 64
#define HH 128
#define NN 64
#define NLAYER 3
#define LC 64          // chunk length
#define NC 128         // chunks per (b,h) sequence
#define LST 137        // kG local-sums f16 row stride
#define SIS 136        // kG sinit f16 [c][n2] row stride

typedef _Float16 half_t;
typedef _Float16 f16x8_t __attribute__((ext_vector_type(8)));
typedef _Float16 f16x4_t __attribute__((ext_vector_type(4)));
typedef _Float16 f16x2_t __attribute__((ext_vector_type(2)));
typedef float    f32x4_t __attribute__((ext_vector_type(4)));

// workspace sizes in float units
#define SZ_WB   ((size_t)HH*NN*2)            // 16384 (per layer)
#define SZ_WGT  ((size_t)NLAYER*256*HH/2)    // 49152 (Wglu f16 [l][g][h])
#define SZ_WOT  ((size_t)DD*HH/2)            // 4096  (WoutT f16 [d][h])
#define SZ_WIT  ((size_t)HH*DD/2)            // 4096  (WinT f16 [h][d])
#define SZ_AM   ((size_t)HH*64*192/2)        // 786432  (f16, per layer)
#define SZ_HT   ((size_t)BB*HH*LL/2)         // 4194304 (f16 [b][h][l])
#define SZ_YT   ((size_t)BB*HH*LL/2)         // 4194304 (f16 [b][h][l])

// ---------------- weight prep ----------------
__global__ __launch_bounds__(256) void kW1(const float* __restrict__ Wglu,
                                           half_t* __restrict__ wgt) {
  int tid = blockIdx.x*256 + threadIdx.x;        // < 3*256*128/8 = 12288
  const float* src = Wglu + (size_t)tid*8;
  f16x8_t v;
  #pragma unroll
  for (int i = 0; i < 8; i++) v[i] = (half_t)src[i];
  *(f16x8_t*)&wgt[(size_t)tid*8] = v;
}
// woT[d][h] = Wout[h][d] f16
__global__ __launch_bounds__(256) void kW2(const float* __restrict__ Wout,
                                           half_t* __restrict__ woT) {
  int tid = blockIdx.x*256 + threadIdx.x;        // < 8192
  int d = tid >> 7, h = tid & 127;
  woT[d*HH + h] = (half_t)Wout[h*DD + d];
}
// wiT[h][d] = Win[d][h] f16
__global__ __launch_bounds__(256) void kW3(const float* __restrict__ Win,
                                           half_t* __restrict__ wiT) {
  int tid = blockIdx.x*256 + threadIdx.x;        // < 8192
  int h = tid >> 6, d = tid & 63;
  wiT[h*DD + d] = (half_t)Win[d*HH + h];
}

// ---------------- kIn: h = x @ W_in + b_in (MFMA) -> hT f16 [b][h][l] ----------------
// Block = 64 l-rows. A = x f16 [64 l][64 d] (LDS), B = wiT [128 h][64 d] (global),
// D staged via zs [h][72] for coalesced [h][l] writes.
__global__ __launch_bounds__(256) void kIn(const float* __restrict__ x,
      const half_t* __restrict__ wiT, const float* __restrict__ bin,
      half_t* __restrict__ hT) {
  __shared__ half_t xs[64*72];
  __shared__ half_t zs[128*72];
  size_t row0 = (size_t)blockIdx.x * 64;
  int t = threadIdx.x;
  #pragma unroll
  for (int i = 0; i < 4; i++) {
    int idx = t + i*256;                  // 0..1023 float4s (64 rows x 16)
    int r = idx >> 4, c4 = idx & 15;
    float4 v = *(const float4*)&x[(row0 + r)*DD + c4*4];
    f16x4_t o = { (half_t)v.x, (half_t)v.y, (half_t)v.z, (half_t)v.w };
    *(f16x4_t*)&xs[r*72 + c4*4] = o;
  }
  __syncthreads();
  int wid = t >> 6, lane = t & 63;
  int lr = lane & 15, lq = lane >> 4, lk = lq*8;
  f32x4_t acc[4][2];
  #pragma unroll
  for (int mr = 0; mr < 4; mr++)
    #pragma unroll
    for (int nc = 0; nc < 2; nc++) {
      float bv = bin[(wid*2 + nc)*16 + lr];
      acc[mr][nc] = (f32x4_t){bv, bv, bv, bv};
    }
  #pragma unroll
  for (int ks = 0; ks < 2; ks++) {
    int k = ks*32 + lk;
    f16x8_t af[4], bf[2];
    #pragma unroll
    for (int mr = 0; mr < 4; mr++) af[mr] = *(const f16x8_t*)&xs[(mr*16 + lr)*72 + k];
    #pragma unroll
    for (int nc = 0; nc < 2; nc++)
      bf[nc] = *(const f16x8_t*)&wiT[(size_t)((wid*2 + nc)*16 + lr)*DD + k];
    #pragma unroll
    for (int mr = 0; mr < 4; mr++)
      #pragma unroll
      for (int nc = 0; nc < 2; nc++)
        acc[mr][nc] = __builtin_amdgcn_mfma_f32_16x16x32_f16(af[mr], bf[nc], acc[mr][nc], 0, 0, 0);
  }
  #pragma unroll
  for (int mr = 0; mr < 4; mr++)
    #pragma unroll
    for (int nc = 0; nc < 2; nc++) {
      int h = (wid*2 + nc)*16 + lr;
      f16x4_t v = { (half_t)acc[mr][nc][0], (half_t)acc[mr][nc][1],
                    (half_t)acc[mr][nc][2], (half_t)acc[mr][nc][3] };
      *(f16x4_t*)&zs[h*72 + mr*16 + lq*4] = v;
    }
  __syncthreads();
  size_t bb = row0 >> 13;
  int l0 = (int)(row0 & 8191);
  int h = t >> 1, hf = t & 1;
  half_t* dst = hT + ((size_t)bb*HH + h)*LL + l0 + hf*32;
  #pragma unroll
  for (int j = 0; j < 4; j++)
    *(f16x8_t*)&dst[j*8] = *(const f16x8_t*)&zs[h*72 + hf*32 + j*8];
}

// ---------------- kP2: ALL layers' SSM params -> wb3, wl3, Amat3 ----------------
__global__ __launch_bounds__(256) void kP2(const float* __restrict__ logdt,
   const float* __restrict__ logA, const float* __restrict__ Aim,
   const float* __restrict__ Cre, const float* __restrict__ Cim,
   float* __restrict__ wb3, float* __restrict__ wl3, half_t* __restrict__ Amat3) {
  __shared__ float ktap[4][64];
  int layer = blockIdx.x >> 5;
  int blk   = blockIdx.x & 31;
  float* wb = wb3 + (size_t)layer*SZ_WB;
  float* wl = wl3 + (size_t)layer*SZ_WB;
  half_t* Amat = Amat3 + (size_t)layer*HH*64*192;
  int t = threadIdx.x;
  int w = t >> 6;
  int n = t & 63;
  int h = blk*4 + w;
  float dt = expf(logdt[layer*HH + h]);
  int idx = (layer*HH + h)*NN + n;
  float ar = -expf(logA[idx]);
  float ai = Aim[idx];
  float er = expf(dt*ar);
  float wr = er*cosf(dt*ai), wi = er*sinf(dt*ai);   // w = exp(dt*A)
  float inv = 1.f/(ar*ar + ai*ai);
  float mr = wr - 1.f, mi = wi;                     // expm1(dtA)
  float tr = (mr*ar + mi*ai)*inv;                   // expm1(dtA)/A
  float ti = (mi*ar - mr*ai)*inv;
  float c0 = Cre[idx], c1 = Cim[idx];
  float cr = c0*tr - c1*ti, ci = c0*ti + c1*tr;     // C_eff
  wb[(h*NN+n)*2] = wr; wb[(h*NN+n)*2+1] = wi;
  float pr = 1.f, pi = 0.f;                         // w^d
  float qr = cr*wr - ci*wi, qi = cr*wi + ci*wr;     // C~ w^{d+1}
  half_t* Ah = Amat + (size_t)h*64*192;
  for (int d = 0; d < 64; d++) {
    float kd = cr*pr - ci*pi;                       // Re(C~ w^d)
    kd += __shfl_xor(kd, 1);  kd += __shfl_xor(kd, 2);  kd += __shfl_xor(kd, 4);
    kd += __shfl_xor(kd, 8);  kd += __shfl_xor(kd, 16); kd += __shfl_xor(kd, 32);
    if (n == 0) ktap[w][d] = 2.f*kd;
    Ah[(size_t)d*192 + 64 + 2*n]   = (half_t)(2.f*qr);
    Ah[(size_t)d*192 + 64 + 2*n+1] = (half_t)(-2.f*qi);
    float npr = pr*wr - pi*wi, npi = pr*wi + pi*wr; pr = npr; pi = npi;
    float nqr = qr*wr - qi*wi, nqi = qr*wi + qi*wr; qr = nqr; qi = nqi;
  }
  wl[(h*NN+n)*2] = pr; wl[(h*NN+n)*2+1] = pi;       // w^64
  __syncthreads();
  {
    int l = n;
    half_t* row = Ah + (size_t)l*192;
    for (int m = 0; m < 64; m++)
      row[m] = (half_t)((m <= l) ? ktap[w][l - m] : 0.f);
  }
}

// ---------------- kG: FUSED states GEMM + scan + output GEMM (512 thr, 76KB LDS) ----------------
__global__ __launch_bounds__(512) void kG(const half_t* __restrict__ hT,
      const float* __restrict__ wb, const float* __restrict__ wl,
      const half_t* __restrict__ Amat, half_t* __restrict__ yT) {
  __shared__ half_t va[128*72];          // 18432 B
  __shared__ half_t ub[128*72];          // 18432 B
  __shared__ half_t spad[128*LST];       // 35072 B
  __shared__ float  segT[8*128];         //  4096 B
  int t = threadIdx.x;
  int h = blockIdx.x >> 3, b = blockIdx.x & 7;
  // ---- phase 0: V build + U stage
  {
    int n = t >> 3, q8 = t & 7;
    float wr = wb[(h*NN+n)*2], wi = wb[(h*NN+n)*2+1];
    float ar = wr, ai = wi;                      // -> w^8
    #pragma unroll
    for (int i = 0; i < 3; i++) { float nr = ar*ar - ai*ai, ni = 2.f*ar*ai; ar = nr; ai = ni; }
    float pr = 1.f, pi = 0.f;
    for (int e = 0; e < 7 - q8; e++) { float nr = pr*ar - pi*ai, ni = pr*ai + pi*ar; pr = nr; pi = ni; }
    int k0 = (7 - q8)*8;
    for (int i = 0; i < 8; i++) {
      int m = 63 - (k0 + i);
      va[(2*n)*72 + m]   = (half_t)pr;           // Re(w^{63-m})
      va[(2*n+1)*72 + m] = (half_t)pi;
      float nr = pr*wr - pi*wi, ni = pr*wi + pi*wr; pr = nr; pi = ni;
    }
  }
  {
    const half_t* src = hT + ((size_t)b*HH + h)*LL;
    #pragma unroll
    for (int i = 0; i < 2; i++) {
      int idx = t + i*512;
      int row = idx >> 3, off = (idx & 7)*8;
      *(f16x8_t*)&ub[row*72 + off] = *(const f16x8_t*)&src[row*64 + off];
    }
  }
  __syncthreads();
  int wid = t >> 6, lane = t & 63;
  int lr = lane & 15, lq = lane >> 4, lk = lq*8;
  // ---- phase 1: local-states GEMM, 8 waves
  {
    int wr_ = wid & 1, wc = wid >> 1;
    f32x4_t acc[4][2];
    #pragma unroll
    for (int mr = 0; mr < 4; mr++) { acc[mr][0] = (f32x4_t){0.f,0.f,0.f,0.f}; acc[mr][1] = (f32x4_t){0.f,0.f,0.f,0.f}; }
    #pragma unroll
    for (int ks = 0; ks < 2; ks++) {
      int k = ks*32 + lk;
      f16x8_t af[4], bf[2];
      #pragma unroll
      for (int mr = 0; mr < 4; mr++) af[mr] = *(const f16x8_t*)&va[(wr_*64 + mr*16 + lr)*72 + k];
      #pragma unroll
      for (int nc = 0; nc < 2; nc++) bf[nc] = *(const f16x8_t*)&ub[(wc*32 + nc*16 + lr)*72 + k];
      #pragma unroll
      for (int mr = 0; mr < 4; mr++)
        #pragma unroll
        for (int nc = 0; nc < 2; nc++)
          acc[mr][nc] = __builtin_amdgcn_mfma_f32_16x16x32_f16(af[mr], bf[nc], acc[mr][nc], 0, 0, 0);
    }
    #pragma unroll
    for (int mr = 0; mr < 4; mr++)
      #pragma unroll
      for (int nc = 0; nc < 2; nc++)
        #pragma unroll
        for (int r = 0; r < 4; r++)
          spad[(wr_*64 + mr*16 + lq*4 + r)*LST + (wc*32 + nc*16 + lr)] = (half_t)acc[mr][nc][r];
  }
  __syncthreads();
  // ---- phase 2: scan; prefixes in registers; transposed sinit write into spad
  {
    int n = t & 63, seg = t >> 6;
    int c0 = seg*16;
    float w64r = wl[(h*NN+n)*2], w64i = wl[(h*NN+n)*2+1];
    float pregr[16], pregi[16];
    float cr = 0.f, ci = 0.f;
    #pragma unroll
    for (int i = 0; i < 16; i++) {
      int c = c0 + i;
      float lre = (float)spad[(2*n)*LST + c];
      float lim = (float)spad[(2*n+1)*LST + c];
      pregr[i] = cr; pregi[i] = ci;
      float nr = fmaf(w64r, cr, fmaf(-w64i, ci, lre));
      float ni = fmaf(w64i, cr, fmaf(w64r, ci, lim));
      cr = nr; ci = ni;
    }
    segT[seg*128 + 2*n] = cr; segT[seg*128 + 2*n+1] = ci;
    __syncthreads();
    float ar = w64r, ai = w64i;           // -> w64^16
    #pragma unroll
    for (int i = 0; i < 4; i++) { float nr = ar*ar - ai*ai, ni = 2.f*ar*ai; ar = nr; ai = ni; }
    float br = 0.f, bi = 0.f;
    for (int k = 0; k < seg; k++) {
      float tr_ = segT[k*128 + 2*n], ti_ = segT[k*128 + 2*n+1];
      float nr = fmaf(ar, br, fmaf(-ai, bi, tr_));
      float ni = fmaf(ai, br, fmaf(ar, bi, ti_));
      br = nr; bi = ni;
    }
    float wpr = 1.f, wpi = 0.f;
    #pragma unroll
    for (int i = 0; i < 16; i++) {
      int c = c0 + i;
      float sr = pregr[i] + wpr*br - wpi*bi;
      float si = pregi[i] + wpr*bi + wpi*br;
      f16x2_t v = { (half_t)sr, (half_t)si };
      *(f16x2_t*)&spad[c*SIS + 2*n] = v;
      float nr = wpr*w64r - wpi*w64i, ni = wpr*w64i + wpi*w64r;
      wpr = nr; wpi = ni;
    }
  }
  __syncthreads();
  // ---- phase 3: output GEMM, 8 waves
  {
    const half_t* Ag = Amat + (size_t)h*64*192;
    f32x4_t acc[4];
    #pragma unroll
    for (int mr = 0; mr < 4; mr++) acc[mr] = (f32x4_t){0.f,0.f,0.f,0.f};
    int c = wid*16 + lr;
    #pragma unroll
    for (int ks = 0; ks < 6; ks++) {
      int k = ks*32 + lk;
      f16x8_t af[4];
      #pragma unroll
      for (int mr = 0; mr < 4; mr++) af[mr] = *(const f16x8_t*)&Ag[(size_t)(mr*16 + lr)*192 + k];
      f16x8_t bf = (ks < 2) ? *(const f16x8_t*)&ub[c*72 + k]
                            : *(const f16x8_t*)&spad[c*SIS + (k - 64)];
      #pragma unroll
      for (int mr = 0; mr < 4; mr++)
        acc[mr] = __builtin_amdgcn_mfma_f32_16x16x32_f16(af[mr], bf, acc[mr], 0, 0, 0);
    }
    half_t* yp = yT + ((size_t)b*HH + h)*LL;
    #pragma unroll
    for (int mr = 0; mr < 4; mr++) {
      int l0 = mr*16 + lq*4;
      f16x4_t v = { (half_t)acc[mr][0], (half_t)acc[mr][1],
                    (half_t)acc[mr][2], (half_t)acc[mr][3] };
      *(f16x4_t*)&yp[c*64 + l0] = v;
    }
  }
}

// ---------------- kD: skip+gelu+MFMA GLU+residual+rmsnorm; last layer fuses out-GEMM ----------------
// Non-last: writes hT f16. Last: writes out fp32 directly (z f16 -> ylds -> MFMA with woT + bout);
// no hT/hA write. kE eliminated.
__global__ __launch_bounds__(256) void kD(const half_t* __restrict__ yT,
     const half_t* __restrict__ hTin, const float* __restrict__ dskip,
     const half_t* __restrict__ wgt, const float* __restrict__ bglu,
     half_t* __restrict__ hT, const half_t* __restrict__ woT,
     const float* __restrict__ bout, float* __restrict__ out, int last) {
  __shared__ half_t ylds[32][136];
  __shared__ float  zlds[32][133];
  __shared__ float  rnorm[32];
  size_t row0 = (size_t)blockIdx.x * 32;
  int b  = (int)(row0 >> 13);
  int l0 = (int)(row0 & 8191);
  int t = threadIdx.x;
  int h  = t >> 1, hf = t & 1;
  int lbase = hf*16;
  const half_t* yb  = yT   + ((size_t)b*HH + h)*LL + l0 + lbase;
  const half_t* ubp = hTin + ((size_t)b*HH + h)*LL + l0 + lbase;
  f16x8_t ya = *(const f16x8_t*)yb;
  f16x8_t yc = *(const f16x8_t*)(yb + 8);
  f16x8_t ua = *(const f16x8_t*)ubp;
  f16x8_t uc = *(const f16x8_t*)(ubp + 8);
  float d = dskip[h];
  #pragma unroll
  for (int i = 0; i < 8; i++) {
    float v = fmaf((float)ua[i], d, (float)ya[i]);
    float arg = 0.7978845608028654f*(v + 0.044715f*v*v*v);
    arg = fminf(fmaxf(arg, -15.f), 15.f);
    float e = __expf(2.f*arg);
    ylds[lbase + i][h] = (half_t)(0.5f*v*(1.f + (e - 1.f)/(e + 1.f)));
  }
  #pragma unroll
  for (int i = 0; i < 8; i++) {
    float v = fmaf((float)uc[i], d, (float)yc[i]);
    float arg = 0.7978845608028654f*(v + 0.044715f*v*v*v);
    arg = fminf(fmaxf(arg, -15.f), 15.f);
    float e = __expf(2.f*arg);
    ylds[lbase + 8 + i][h] = (half_t)(0.5f*v*(1.f + (e - 1.f)/(e + 1.f)));
  }
  __syncthreads();
  {
    int w = t >> 6, lane = t & 63;
    int lr = lane & 15, lq = lane >> 4;
    f16x8_t af[2][4];
    #pragma unroll
    for (int mt = 0; mt < 2; mt++)
      #pragma unroll
      for (int ks = 0; ks < 4; ks++)
        af[mt][ks] = *(const f16x8_t*)&ylds[mt*16 + lr][ks*32 + lq*8];
    int ntl[4] = { 2*w, 2*w+1, 2*w+8, 2*w+9 };
    f32x4_t acc[2][4];
    #pragma unroll
    for (int mt = 0; mt < 2; mt++)
      #pragma unroll
      for (int p = 0; p < 4; p++) acc[mt][p] = (f32x4_t){0.f,0.f,0.f,0.f};
    #pragma unroll
    for (int p = 0; p < 4; p++) {
      int nt = ntl[p];
      #pragma unroll
      for (int ks = 0; ks < 4; ks++) {
        f16x8_t bf = *(const f16x8_t*)&wgt[(size_t)(nt*16 + lr)*HH + ks*32 + lq*8];
        #pragma unroll
        for (int mt = 0; mt < 2; mt++)
          acc[mt][p] = __builtin_amdgcn_mfma_f32_16x16x32_f16(af[mt][ks], bf, acc[mt][p], 0, 0, 0);
      }
    }
    #pragma unroll
    for (int p = 0; p < 2; p++) {
      int col = 32*w + p*16 + lr;
      float ba = bglu[col], bg = bglu[col + 128];
      #pragma unroll
      for (int mt = 0; mt < 2; mt++)
        #pragma unroll
        for (int r = 0; r < 4; r++) {
          float a = acc[mt][p][r]   + ba;
          float g = acc[mt][p+2][r] + bg;
          float s = 1.f/(1.f + __expf(-g));
          zlds[mt*16 + lq*4 + r][col] = a*s;
        }
    }
  }
  __syncthreads();
  #pragma unroll
  for (int i = 0; i < 8; i++) zlds[lbase + i][h]     += (float)ua[i];
  #pragma unroll
  for (int i = 0; i < 8; i++) zlds[lbase + 8 + i][h] += (float)uc[i];
  __syncthreads();
  #pragma unroll
  for (int i = 0; i < 4; i++) {
    int idx = i*256 + t;
    int row = idx >> 5, c4 = idx & 31;
    const float4 f = *reinterpret_cast<const float4*>(&zlds[row][c4*4]);
    float s = fmaf(f.x, f.x, fmaf(f.y, f.y, fmaf(f.z, f.z, f.w*f.w)));
    s += __shfl_xor(s, 1); s += __shfl_xor(s, 2); s += __shfl_xor(s, 4);
    s += __shfl_xor(s, 8); s += __shfl_xor(s, 16);
    if ((t & 31) == 0) rnorm[row] = s;
  }
  __syncthreads();
  f16x8_t o0, o1;
  #pragma unroll
  for (int i = 0; i < 8; i++) {
    float sc = 11.313708498984761f / fmaxf(sqrtf(rnorm[lbase + i]), 1e-12f);
    o0[i] = (half_t)(zlds[lbase + i][h]*sc);
  }
  #pragma unroll
  for (int i = 0; i < 8; i++) {
    float sc = 11.313708498984761f / fmaxf(sqrtf(rnorm[lbase + 8 + i]), 1e-12f);
    o1[i] = (half_t)(zlds[lbase + 8 + i][h]*sc);
  }
  if (!last) {
    half_t* hb = hT + ((size_t)b*HH + h)*LL + l0 + lbase;
    *(f16x8_t*)hb = o0;
    *(f16x8_t*)(hb + 8) = o1;
  } else {
    // stage scaled z f16 into ylds (dead since stage-2 reads), then out-GEMM
    #pragma unroll
    for (int i = 0; i < 8; i++) ylds[lbase + i][h]     = o0[i];
    #pragma unroll
    for (int i = 0; i < 8; i++) ylds[lbase + 8 + i][h] = o1[i];
    __syncthreads();
    int w = t >> 6, lane = t & 63;
    int lr = lane & 15, lq = lane >> 4;
    int dd = w*16 + lr;
    f32x4_t oacc[2];
    float bv = bout[dd];
    oacc[0] = (f32x4_t){bv, bv, bv, bv};
    oacc[1] = (f32x4_t){bv, bv, bv, bv};
    #pragma unroll
    for (int ks = 0; ks < 4; ks++) {
      int k = ks*32 + lq*8;
      f16x8_t bf = *(const f16x8_t*)&woT[(size_t)dd*HH + k];
      #pragma unroll
      for (int mt = 0; mt < 2; mt++) {
        f16x8_t af = *(const f16x8_t*)&ylds[mt*16 + lr][k];
        oacc[mt] = __builtin_amdgcn_mfma_f32_16x16x32_f16(af, bf, oacc[mt], 0, 0, 0);
      }
    }
    #pragma unroll
    for (int mt = 0; mt < 2; mt++)
      #pragma unroll
      for (int r = 0; r < 4; r++)
        out[(row0 + mt*16 + lq*4 + r)*DD + dd] = oacc[mt][r];
  }
}

extern "C" void kernel_launch(void* const* d_in, const int* in_sizes, int n_in,
                              void* d_out, int out_size, void* d_ws, size_t ws_size,
                              hipStream_t stream) {
  const float* x     = (const float*)d_in[0];
  const float* Win   = (const float*)d_in[1];
  const float* bin   = (const float*)d_in[2];
  const float* logdt = (const float*)d_in[3];
  const float* logA  = (const float*)d_in[4];
  const float* Aim   = (const float*)d_in[5];
  const float* Cre   = (const float*)d_in[6];
  const float* Cim   = (const float*)d_in[7];
  const float* Dsk   = (const float*)d_in[8];
  const float* Wglu  = (const float*)d_in[9];
  const float* bglu  = (const float*)d_in[10];
  const float* Wout  = (const float*)d_in[11];
  const float* bout  = (const float*)d_in[12];
  float* out = (float*)d_out;

  // Total ≈ 43.6 MB (hA/kE eliminated; safe under the proven 104.2MB bound)
  float* ws   = (float*)d_ws;
  float* wb3  = ws;                          // 3*16384
  float* wl3  = wb3 + 3*SZ_WB;               // 3*16384
  float* wgtF = wl3 + 3*SZ_WB;               // 49152
  float* woTF = wgtF + SZ_WGT;               // 4096
  float* wiTF = woTF + SZ_WOT;               // 4096
  float* amF  = wiTF + SZ_WIT;               // Amat3 f16: 3*786432 (9.4MB)
  float* htF  = amF + 3*SZ_AM;               // hT f16 (16.8MB)
  float* ytF  = htF + SZ_HT;                 // yT f16 (16.8MB)
  half_t* wgt    = (half_t*)wgtF;
  half_t* woT    = (half_t*)woTF;
  half_t* wiT    = (half_t*)wiTF;
  half_t* Amat3  = (half_t*)amF;
  half_t* hT     = (half_t*)htF;
  half_t* yT     = (half_t*)ytF;

  kW1<<<dim3(48), dim3(256), 0, stream>>>(Wglu, wgt);
  kW2<<<dim3(32), dim3(256), 0, stream>>>(Wout, woT);
  kW3<<<dim3(32), dim3(256), 0, stream>>>(Win,  wiT);
  kP2<<<dim3(96), dim3(256), 0, stream>>>(logdt, logA, Aim, Cre, Cim, wb3, wl3, Amat3);
  kIn<<<dim3(1024), dim3(256), 0, stream>>>(x, wiT, bin, hT);

  for (int layer = 0; layer < NLAYER; ++layer) {
    const float* wb = wb3 + (size_t)layer*SZ_WB;
    const float* wl = wl3 + (size_t)layer*SZ_WB;
    const half_t* Amat = Amat3 + (size_t)layer*HH*64*192;
    kG<<<dim3(1024), dim3(512), 0, stream>>>(hT, wb, wl, Amat, yT);
    kD<<<dim3(2048), dim3(256), 0, stream>>>(yT, hT, Dsk + layer*HH,
                       wgt + (size_t)layer*256*HH,
                       bglu + layer*2*HH, hT, woT, bout, out,
                       (layer == NLAYER-1) ? 1 : 0);
  }
}

// Round 16
// 255.469 us; speedup vs baseline: 1.2795x; 1.0475x over previous
//
#include <hip/hip_runtime.h>
#include <math.h>

#define BB 8
#define LL 8192
#define DD 64
#define HH 128
#define NN 64
#define NLAYER 3
#define LC 64          // chunk length
#define NC 128         // chunks per (b,h) sequence
#define LST 137        // kG local-sums f16 row stride
#define SIS 136        // kG sinit f16 [c][n2] row stride

typedef _Float16 half_t;
typedef _Float16 f16x8_t __attribute__((ext_vector_type(8)));
typedef _Float16 f16x4_t __attribute__((ext_vector_type(4)));
typedef _Float16 f16x2_t __attribute__((ext_vector_type(2)));
typedef float    f32x4_t __attribute__((ext_vector_type(4)));

// workspace sizes in float units
#define SZ_WB   ((size_t)HH*NN*2)            // 16384 (per layer)
#define SZ_WGT  ((size_t)NLAYER*256*HH/2)    // 49152 (Wglu f16 [l][g][h])
#define SZ_WOT  ((size_t)DD*HH/2)            // 4096  (WoutT f16 [d][h])
#define SZ_WIT  ((size_t)HH*DD/2)            // 4096  (WinT f16 [h][d])
#define SZ_AM   ((size_t)HH*64*192/2)        // 786432  (f16, per layer)
#define SZ_HT   ((size_t)BB*HH*LL/2)         // 4194304 (f16 [b][h][l])
#define SZ_YT   ((size_t)BB*HH*LL/2)         // 4194304 (f16 [b][h][l])

// ---------------- weight prep ----------------
__global__ __launch_bounds__(256) void kW1(const float* __restrict__ Wglu,
                                           half_t* __restrict__ wgt) {
  int tid = blockIdx.x*256 + threadIdx.x;        // < 3*256*128/8 = 12288
  const float* src = Wglu + (size_t)tid*8;
  f16x8_t v;
  #pragma unroll
  for (int i = 0; i < 8; i++) v[i] = (half_t)src[i];
  *(f16x8_t*)&wgt[(size_t)tid*8] = v;
}
// woT[d][h] = Wout[h][d] f16
__global__ __launch_bounds__(256) void kW2(const float* __restrict__ Wout,
                                           half_t* __restrict__ woT) {
  int tid = blockIdx.x*256 + threadIdx.x;        // < 8192
  int d = tid >> 7, h = tid & 127;
  woT[d*HH + h] = (half_t)Wout[h*DD + d];
}
// wiT[h][d] = Win[d][h] f16
__global__ __launch_bounds__(256) void kW3(const float* __restrict__ Win,
                                           half_t* __restrict__ wiT) {
  int tid = blockIdx.x*256 + threadIdx.x;        // < 8192
  int h = tid >> 6, d = tid & 63;
  wiT[h*DD + d] = (half_t)Win[d*HH + h];
}

// ---------------- kIn: h = x @ W_in + b_in (MFMA) -> hT f16 [b][h][l] ----------------
__global__ __launch_bounds__(256) void kIn(const float* __restrict__ x,
      const half_t* __restrict__ wiT, const float* __restrict__ bin,
      half_t* __restrict__ hT) {
  __shared__ half_t xs[64*72];
  __shared__ half_t zs[128*72];
  size_t row0 = (size_t)blockIdx.x * 64;
  int t = threadIdx.x;
  #pragma unroll
  for (int i = 0; i < 4; i++) {
    int idx = t + i*256;                  // 0..1023 float4s (64 rows x 16)
    int r = idx >> 4, c4 = idx & 15;
    float4 v = *(const float4*)&x[(row0 + r)*DD + c4*4];
    f16x4_t o = { (half_t)v.x, (half_t)v.y, (half_t)v.z, (half_t)v.w };
    *(f16x4_t*)&xs[r*72 + c4*4] = o;
  }
  __syncthreads();
  int wid = t >> 6, lane = t & 63;
  int lr = lane & 15, lq = lane >> 4, lk = lq*8;
  f32x4_t acc[4][2];
  #pragma unroll
  for (int mr = 0; mr < 4; mr++)
    #pragma unroll
    for (int nc = 0; nc < 2; nc++) {
      float bv = bin[(wid*2 + nc)*16 + lr];
      acc[mr][nc] = (f32x4_t){bv, bv, bv, bv};
    }
  #pragma unroll
  for (int ks = 0; ks < 2; ks++) {
    int k = ks*32 + lk;
    f16x8_t af[4], bf[2];
    #pragma unroll
    for (int mr = 0; mr < 4; mr++) af[mr] = *(const f16x8_t*)&xs[(mr*16 + lr)*72 + k];
    #pragma unroll
    for (int nc = 0; nc < 2; nc++)
      bf[nc] = *(const f16x8_t*)&wiT[(size_t)((wid*2 + nc)*16 + lr)*DD + k];
    #pragma unroll
    for (int mr = 0; mr < 4; mr++)
      #pragma unroll
      for (int nc = 0; nc < 2; nc++)
        acc[mr][nc] = __builtin_amdgcn_mfma_f32_16x16x32_f16(af[mr], bf[nc], acc[mr][nc], 0, 0, 0);
  }
  #pragma unroll
  for (int mr = 0; mr < 4; mr++)
    #pragma unroll
    for (int nc = 0; nc < 2; nc++) {
      int h = (wid*2 + nc)*16 + lr;
      f16x4_t v = { (half_t)acc[mr][nc][0], (half_t)acc[mr][nc][1],
                    (half_t)acc[mr][nc][2], (half_t)acc[mr][nc][3] };
      *(f16x4_t*)&zs[h*72 + mr*16 + lq*4] = v;
    }
  __syncthreads();
  size_t bb = row0 >> 13;
  int l0 = (int)(row0 & 8191);
  int h = t >> 1, hf = t & 1;
  half_t* dst = hT + ((size_t)bb*HH + h)*LL + l0 + hf*32;
  #pragma unroll
  for (int j = 0; j < 4; j++)
    *(f16x8_t*)&dst[j*8] = *(const f16x8_t*)&zs[h*72 + hf*32 + j*8];
}

// ---------------- kP2: ALL layers' SSM params; vectorized Amat writes via LDS staging ----------------
__global__ __launch_bounds__(256) void kP2(const float* __restrict__ logdt,
   const float* __restrict__ logA, const float* __restrict__ Aim,
   const float* __restrict__ Cre, const float* __restrict__ Cim,
   float* __restrict__ wb3, float* __restrict__ wl3, half_t* __restrict__ Amat3) {
  __shared__ float  ktap[4][64];
  __shared__ half_t gst[4][64][128];    // 64KB: G rows staged per local-h
  int layer = blockIdx.x >> 5;
  int blk   = blockIdx.x & 31;
  float* wb = wb3 + (size_t)layer*SZ_WB;
  float* wl = wl3 + (size_t)layer*SZ_WB;
  half_t* Amat = Amat3 + (size_t)layer*HH*64*192;
  int t = threadIdx.x;
  int w = t >> 6;
  int n = t & 63;
  int h = blk*4 + w;
  float dt = expf(logdt[layer*HH + h]);
  int idx = (layer*HH + h)*NN + n;
  float ar = -expf(logA[idx]);
  float ai = Aim[idx];
  float er = expf(dt*ar);
  float wr = er*cosf(dt*ai), wi = er*sinf(dt*ai);   // w = exp(dt*A)
  float inv = 1.f/(ar*ar + ai*ai);
  float mr = wr - 1.f, mi = wi;                     // expm1(dtA)
  float tr = (mr*ar + mi*ai)*inv;                   // expm1(dtA)/A
  float ti = (mi*ar - mr*ai)*inv;
  float c0 = Cre[idx], c1 = Cim[idx];
  float cr = c0*tr - c1*ti, ci = c0*ti + c1*tr;     // C_eff
  wb[(h*NN+n)*2] = wr; wb[(h*NN+n)*2+1] = wi;
  float pr = 1.f, pi = 0.f;                         // w^d
  float qr = cr*wr - ci*wi, qi = cr*wi + ci*wr;     // C~ w^{d+1}
  for (int d = 0; d < 64; d++) {
    float kd = cr*pr - ci*pi;                       // Re(C~ w^d)
    kd += __shfl_xor(kd, 1);  kd += __shfl_xor(kd, 2);  kd += __shfl_xor(kd, 4);
    kd += __shfl_xor(kd, 8);  kd += __shfl_xor(kd, 16); kd += __shfl_xor(kd, 32);
    if (n == 0) ktap[w][d] = 2.f*kd;
    f16x2_t g2 = { (half_t)(2.f*qr), (half_t)(-2.f*qi) };
    *(f16x2_t*)&gst[w][d][2*n] = g2;                // lanes 4B apart: bank-spread
    float npr = pr*wr - pi*wi, npi = pr*wi + pi*wr; pr = npr; pi = npi;
    float nqr = qr*wr - qi*wi, nqi = qr*wi + qi*wr; qr = nqr; qi = nqi;
  }
  wl[(h*NN+n)*2] = pr; wl[(h*NN+n)*2+1] = pi;       // w^64
  __syncthreads();
  // G copy: 4h x 64l x 16 f16x8 = 4096 stores, 16/thread, fully coalesced
  #pragma unroll
  for (int i = 0; i < 16; i++) {
    int idx2 = t + i*256;
    int hh = idx2 >> 10;
    int rem = idx2 & 1023;
    int l = rem >> 4, m8 = rem & 15;
    half_t* Ahh = Amat + (size_t)(blk*4 + hh)*64*192;
    *(f16x8_t*)&Ahh[(size_t)l*192 + 64 + m8*8] = *(const f16x8_t*)&gst[hh][l][m8*8];
  }
  // Toeplitz: 4h x 64l x 8 f16x8 = 2048 stores, 8/thread
  #pragma unroll
  for (int i = 0; i < 8; i++) {
    int idx2 = t + i*256;
    int hh = idx2 >> 9;
    int rem = idx2 & 511;
    int l = rem >> 3, m8 = rem & 7;
    half_t* Ahh = Amat + (size_t)(blk*4 + hh)*64*192;
    f16x8_t v;
    #pragma unroll
    for (int j = 0; j < 8; j++) {
      int m = m8*8 + j;
      v[j] = (half_t)((m <= l) ? ktap[hh][l - m] : 0.f);
    }
    *(f16x8_t*)&Ahh[(size_t)l*192 + m8*8] = v;
  }
}

// ---------------- kG: FUSED states GEMM + scan + output GEMM (512 thr, 76KB LDS) ----------------
// Round-16 change: phase-3 y staged into va (dead after phase 1) -> coalesced 32B yT stores.
__global__ __launch_bounds__(512) void kG(const half_t* __restrict__ hT,
      const float* __restrict__ wb, const float* __restrict__ wl,
      const half_t* __restrict__ Amat, half_t* __restrict__ yT) {
  __shared__ half_t va[128*72];          // 18432 B (V matrix; reused as y staging [c][72])
  __shared__ half_t ub[128*72];          // 18432 B
  __shared__ half_t spad[128*LST];       // 35072 B
  __shared__ float  segT[8*128];         //  4096 B
  int t = threadIdx.x;
  int h = blockIdx.x >> 3, b = blockIdx.x & 7;
  // ---- phase 0: V build + U stage
  {
    int n = t >> 3, q8 = t & 7;
    float wr = wb[(h*NN+n)*2], wi = wb[(h*NN+n)*2+1];
    float ar = wr, ai = wi;                      // -> w^8
    #pragma unroll
    for (int i = 0; i < 3; i++) { float nr = ar*ar - ai*ai, ni = 2.f*ar*ai; ar = nr; ai = ni; }
    float pr = 1.f, pi = 0.f;
    for (int e = 0; e < 7 - q8; e++) { float nr = pr*ar - pi*ai, ni = pr*ai + pi*ar; pr = nr; pi = ni; }
    int k0 = (7 - q8)*8;
    for (int i = 0; i < 8; i++) {
      int m = 63 - (k0 + i);
      va[(2*n)*72 + m]   = (half_t)pr;           // Re(w^{63-m})
      va[(2*n+1)*72 + m] = (half_t)pi;
      float nr = pr*wr - pi*wi, ni = pr*wi + pi*wr; pr = nr; pi = ni;
    }
  }
  {
    const half_t* src = hT + ((size_t)b*HH + h)*LL;
    #pragma unroll
    for (int i = 0; i < 2; i++) {
      int idx = t + i*512;
      int row = idx >> 3, off = (idx & 7)*8;
      *(f16x8_t*)&ub[row*72 + off] = *(const f16x8_t*)&src[row*64 + off];
    }
  }
  __syncthreads();
  int wid = t >> 6, lane = t & 63;
  int lr = lane & 15, lq = lane >> 4, lk = lq*8;
  // ---- phase 1: local-states GEMM, 8 waves
  {
    int wr_ = wid & 1, wc = wid >> 1;
    f32x4_t acc[4][2];
    #pragma unroll
    for (int mr = 0; mr < 4; mr++) { acc[mr][0] = (f32x4_t){0.f,0.f,0.f,0.f}; acc[mr][1] = (f32x4_t){0.f,0.f,0.f,0.f}; }
    #pragma unroll
    for (int ks = 0; ks < 2; ks++) {
      int k = ks*32 + lk;
      f16x8_t af[4], bf[2];
      #pragma unroll
      for (int mr = 0; mr < 4; mr++) af[mr] = *(const f16x8_t*)&va[(wr_*64 + mr*16 + lr)*72 + k];
      #pragma unroll
      for (int nc = 0; nc < 2; nc++) bf[nc] = *(const f16x8_t*)&ub[(wc*32 + nc*16 + lr)*72 + k];
      #pragma unroll
      for (int mr = 0; mr < 4; mr++)
        #pragma unroll
        for (int nc = 0; nc < 2; nc++)
          acc[mr][nc] = __builtin_amdgcn_mfma_f32_16x16x32_f16(af[mr], bf[nc], acc[mr][nc], 0, 0, 0);
    }
    #pragma unroll
    for (int mr = 0; mr < 4; mr++)
      #pragma unroll
      for (int nc = 0; nc < 2; nc++)
        #pragma unroll
        for (int r = 0; r < 4; r++)
          spad[(wr_*64 + mr*16 + lq*4 + r)*LST + (wc*32 + nc*16 + lr)] = (half_t)acc[mr][nc][r];
  }
  __syncthreads();
  // ---- phase 2: scan; prefixes in registers; transposed sinit write into spad
  {
    int n = t & 63, seg = t >> 6;
    int c0 = seg*16;
    float w64r = wl[(h*NN+n)*2], w64i = wl[(h*NN+n)*2+1];
    float pregr[16], pregi[16];
    float cr = 0.f, ci = 0.f;
    #pragma unroll
    for (int i = 0; i < 16; i++) {
      int c = c0 + i;
      float lre = (float)spad[(2*n)*LST + c];
      float lim = (float)spad[(2*n+1)*LST + c];
      pregr[i] = cr; pregi[i] = ci;
      float nr = fmaf(w64r, cr, fmaf(-w64i, ci, lre));
      float ni = fmaf(w64i, cr, fmaf(w64r, ci, lim));
      cr = nr; ci = ni;
    }
    segT[seg*128 + 2*n] = cr; segT[seg*128 + 2*n+1] = ci;
    __syncthreads();
    float ar = w64r, ai = w64i;           // -> w64^16
    #pragma unroll
    for (int i = 0; i < 4; i++) { float nr = ar*ar - ai*ai, ni = 2.f*ar*ai; ar = nr; ai = ni; }
    float br = 0.f, bi = 0.f;
    for (int k = 0; k < seg; k++) {
      float tr_ = segT[k*128 + 2*n], ti_ = segT[k*128 + 2*n+1];
      float nr = fmaf(ar, br, fmaf(-ai, bi, tr_));
      float ni = fmaf(ai, br, fmaf(ar, bi, ti_));
      br = nr; bi = ni;
    }
    float wpr = 1.f, wpi = 0.f;
    #pragma unroll
    for (int i = 0; i < 16; i++) {
      int c = c0 + i;
      float sr = pregr[i] + wpr*br - wpi*bi;
      float si = pregi[i] + wpr*bi + wpi*br;
      f16x2_t v = { (half_t)sr, (half_t)si };
      *(f16x2_t*)&spad[c*SIS + 2*n] = v;
      float nr = wpr*w64r - wpi*w64i, ni = wpr*w64i + wpi*w64r;
      wpr = nr; wpi = ni;
    }
  }
  __syncthreads();
  // ---- phase 3: output GEMM, 8 waves; results staged into va [c][72]
  {
    const half_t* Ag = Amat + (size_t)h*64*192;
    f32x4_t acc[4];
    #pragma unroll
    for (int mr = 0; mr < 4; mr++) acc[mr] = (f32x4_t){0.f,0.f,0.f,0.f};
    int c = wid*16 + lr;
    #pragma unroll
    for (int ks = 0; ks < 6; ks++) {
      int k = ks*32 + lk;
      f16x8_t af[4];
      #pragma unroll
      for (int mr = 0; mr < 4; mr++) af[mr] = *(const f16x8_t*)&Ag[(size_t)(mr*16 + lr)*192 + k];
      f16x8_t bf = (ks < 2) ? *(const f16x8_t*)&ub[c*72 + k]
                            : *(const f16x8_t*)&spad[c*SIS + (k - 64)];
      #pragma unroll
      for (int mr = 0; mr < 4; mr++)
        acc[mr] = __builtin_amdgcn_mfma_f32_16x16x32_f16(af[mr], bf, acc[mr], 0, 0, 0);
    }
    #pragma unroll
    for (int mr = 0; mr < 4; mr++) {
      int l0 = mr*16 + lq*4;
      f16x4_t v = { (half_t)acc[mr][0], (half_t)acc[mr][1],
                    (half_t)acc[mr][2], (half_t)acc[mr][3] };
      *(f16x4_t*)&va[c*72 + l0] = v;
    }
  }
  __syncthreads();
  // ---- coalesced yT write: thread t -> c = t>>2, 16 halves (32B), adjacent lanes contiguous
  {
    half_t* yp = yT + ((size_t)b*HH + h)*LL;
    int c = t >> 2, q = t & 3;
    const half_t* src = &va[c*72 + q*16];
    f16x8_t v0 = *(const f16x8_t*)src;
    f16x8_t v1 = *(const f16x8_t*)(src + 8);
    *(f16x8_t*)&yp[c*64 + q*16]     = v0;
    *(f16x8_t*)&yp[c*64 + q*16 + 8] = v1;
  }
}

// ---------------- kD: skip+gelu+MFMA GLU+residual+rmsnorm; last layer fuses out-GEMM ----------------
__global__ __launch_bounds__(256) void kD(const half_t* __restrict__ yT,
     const half_t* __restrict__ hTin, const float* __restrict__ dskip,
     const half_t* __restrict__ wgt, const float* __restrict__ bglu,
     half_t* __restrict__ hT, const half_t* __restrict__ woT,
     const float* __restrict__ bout, float* __restrict__ out, int last) {
  __shared__ half_t ylds[32][136];
  __shared__ float  zlds[32][133];
  __shared__ float  rnorm[32];
  size_t row0 = (size_t)blockIdx.x * 32;
  int b  = (int)(row0 >> 13);
  int l0 = (int)(row0 & 8191);
  int t = threadIdx.x;
  int h  = t >> 1, hf = t & 1;
  int lbase = hf*16;
  const half_t* yb  = yT   + ((size_t)b*HH + h)*LL + l0 + lbase;
  const half_t* ubp = hTin + ((size_t)b*HH + h)*LL + l0 + lbase;
  f16x8_t ya = *(const f16x8_t*)yb;
  f16x8_t yc = *(const f16x8_t*)(yb + 8);
  f16x8_t ua = *(const f16x8_t*)ubp;
  f16x8_t uc = *(const f16x8_t*)(ubp + 8);
  float d = dskip[h];
  #pragma unroll
  for (int i = 0; i < 8; i++) {
    float v = fmaf((float)ua[i], d, (float)ya[i]);
    float arg = 0.7978845608028654f*(v + 0.044715f*v*v*v);
    arg = fminf(fmaxf(arg, -15.f), 15.f);
    float e = __expf(2.f*arg);
    ylds[lbase + i][h] = (half_t)(0.5f*v*(1.f + (e - 1.f)/(e + 1.f)));
  }
  #pragma unroll
  for (int i = 0; i < 8; i++) {
    float v = fmaf((float)uc[i], d, (float)yc[i]);
    float arg = 0.7978845608028654f*(v + 0.044715f*v*v*v);
    arg = fminf(fmaxf(arg, -15.f), 15.f);
    float e = __expf(2.f*arg);
    ylds[lbase + 8 + i][h] = (half_t)(0.5f*v*(1.f + (e - 1.f)/(e + 1.f)));
  }
  __syncthreads();
  {
    int w = t >> 6, lane = t & 63;
    int lr = lane & 15, lq = lane >> 4;
    f16x8_t af[2][4];
    #pragma unroll
    for (int mt = 0; mt < 2; mt++)
      #pragma unroll
      for (int ks = 0; ks < 4; ks++)
        af[mt][ks] = *(const f16x8_t*)&ylds[mt*16 + lr][ks*32 + lq*8];
    int ntl[4] = { 2*w, 2*w+1, 2*w+8, 2*w+9 };
    f32x4_t acc[2][4];
    #pragma unroll
    for (int mt = 0; mt < 2; mt++)
      #pragma unroll
      for (int p = 0; p < 4; p++) acc[mt][p] = (f32x4_t){0.f,0.f,0.f,0.f};
    #pragma unroll
    for (int p = 0; p < 4; p++) {
      int nt = ntl[p];
      #pragma unroll
      for (int ks = 0; ks < 4; ks++) {
        f16x8_t bf = *(const f16x8_t*)&wgt[(size_t)(nt*16 + lr)*HH + ks*32 + lq*8];
        #pragma unroll
        for (int mt = 0; mt < 2; mt++)
          acc[mt][p] = __builtin_amdgcn_mfma_f32_16x16x32_f16(af[mt][ks], bf, acc[mt][p], 0, 0, 0);
      }
    }
    #pragma unroll
    for (int p = 0; p < 2; p++) {
      int col = 32*w + p*16 + lr;
      float ba = bglu[col], bg = bglu[col + 128];
      #pragma unroll
      for (int mt = 0; mt < 2; mt++)
        #pragma unroll
        for (int r = 0; r < 4; r++) {
          float a = acc[mt][p][r]   + ba;
          float g = acc[mt][p+2][r] + bg;
          float s = 1.f/(1.f + __expf(-g));
          zlds[mt*16 + lq*4 + r][col] = a*s;
        }
    }
  }
  __syncthreads();
  #pragma unroll
  for (int i = 0; i < 8; i++) zlds[lbase + i][h]     += (float)ua[i];
  #pragma unroll
  for (int i = 0; i < 8; i++) zlds[lbase + 8 + i][h] += (float)uc[i];
  __syncthreads();
  #pragma unroll
  for (int i = 0; i < 4; i++) {
    int idx = i*256 + t;
    int row = idx >> 5, c4 = idx & 31;
    const float4 f = *reinterpret_cast<const float4*>(&zlds[row][c4*4]);
    float s = fmaf(f.x, f.x, fmaf(f.y, f.y, fmaf(f.z, f.z, f.w*f.w)));
    s += __shfl_xor(s, 1); s += __shfl_xor(s, 2); s += __shfl_xor(s, 4);
    s += __shfl_xor(s, 8); s += __shfl_xor(s, 16);
    if ((t & 31) == 0) rnorm[row] = s;
  }
  __syncthreads();
  f16x8_t o0, o1;
  #pragma unroll
  for (int i = 0; i < 8; i++) {
    float sc = 11.313708498984761f / fmaxf(sqrtf(rnorm[lbase + i]), 1e-12f);
    o0[i] = (half_t)(zlds[lbase + i][h]*sc);
  }
  #pragma unroll
  for (int i = 0; i < 8; i++) {
    float sc = 11.313708498984761f / fmaxf(sqrtf(rnorm[lbase + 8 + i]), 1e-12f);
    o1[i] = (half_t)(zlds[lbase + 8 + i][h]*sc);
  }
  if (!last) {
    half_t* hb = hT + ((size_t)b*HH + h)*LL + l0 + lbase;
    *(f16x8_t*)hb = o0;
    *(f16x8_t*)(hb + 8) = o1;
  } else {
    #pragma unroll
    for (int i = 0; i < 8; i++) ylds[lbase + i][h]     = o0[i];
    #pragma unroll
    for (int i = 0; i < 8; i++) ylds[lbase + 8 + i][h] = o1[i];
    __syncthreads();
    int w = t >> 6, lane = t & 63;
    int lr = lane & 15, lq = lane >> 4;
    int dd = w*16 + lr;
    f32x4_t oacc[2];
    float bv = bout[dd];
    oacc[0] = (f32x4_t){bv, bv, bv, bv};
    oacc[1] = (f32x4_t){bv, bv, bv, bv};
    #pragma unroll
    for (int ks = 0; ks < 4; ks++) {
      int k = ks*32 + lq*8;
      f16x8_t bf = *(const f16x8_t*)&woT[(size_t)dd*HH + k];
      #pragma unroll
      for (int mt = 0; mt < 2; mt++) {
        f16x8_t af = *(const f16x8_t*)&ylds[mt*16 + lr][k];
        oacc[mt] = __builtin_amdgcn_mfma_f32_16x16x32_f16(af, bf, oacc[mt], 0, 0, 0);
      }
    }
    #pragma unroll
    for (int mt = 0; mt < 2; mt++)
      #pragma unroll
      for (int r = 0; r < 4; r++)
        out[(row0 + mt*16 + lq*4 + r)*DD + dd] = oacc[mt][r];
  }
}

extern "C" void kernel_launch(void* const* d_in, const int* in_sizes, int n_in,
                              void* d_out, int out_size, void* d_ws, size_t ws_size,
                              hipStream_t stream) {
  const float* x     = (const float*)d_in[0];
  const float* Win   = (const float*)d_in[1];
  const float* bin   = (const float*)d_in[2];
  const float* logdt = (const float*)d_in[3];
  const float* logA  = (const float*)d_in[4];
  const float* Aim   = (const float*)d_in[5];
  const float* Cre   = (const float*)d_in[6];
  const float* Cim   = (const float*)d_in[7];
  const float* Dsk   = (const float*)d_in[8];
  const float* Wglu  = (const float*)d_in[9];
  const float* bglu  = (const float*)d_in[10];
  const float* Wout  = (const float*)d_in[11];
  const float* bout  = (const float*)d_in[12];
  float* out = (float*)d_out;

  // Total ≈ 43.6 MB (safe under the proven 104.2MB bound)
  float* ws   = (float*)d_ws;
  float* wb3  = ws;                          // 3*16384
  float* wl3  = wb3 + 3*SZ_WB;               // 3*16384
  float* wgtF = wl3 + 3*SZ_WB;               // 49152
  float* woTF = wgtF + SZ_WGT;               // 4096
  float* wiTF = woTF + SZ_WOT;               // 4096
  float* amF  = wiTF + SZ_WIT;               // Amat3 f16: 3*786432 (9.4MB)
  float* htF  = amF + 3*SZ_AM;               // hT f16 (16.8MB)
  float* ytF  = htF + SZ_HT;                 // yT f16 (16.8MB)
  half_t* wgt    = (half_t*)wgtF;
  half_t* woT    = (half_t*)woTF;
  half_t* wiT    = (half_t*)wiTF;
  half_t* Amat3  = (half_t*)amF;
  half_t* hT     = (half_t*)htF;
  half_t* yT     = (half_t*)ytF;

  kW1<<<dim3(48), dim3(256), 0, stream>>>(Wglu, wgt);
  kW2<<<dim3(32), dim3(256), 0, stream>>>(Wout, woT);
  kW3<<<dim3(32), dim3(256), 0, stream>>>(Win,  wiT);
  kP2<<<dim3(96), dim3(256), 0, stream>>>(logdt, logA, Aim, Cre, Cim, wb3, wl3, Amat3);
  kIn<<<dim3(1024), dim3(256), 0, stream>>>(x, wiT, bin, hT);

  for (int layer = 0; layer < NLAYER; ++layer) {
    const float* wb = wb3 + (size_t)layer*SZ_WB;
    const float* wl = wl3 + (size_t)layer*SZ_WB;
    const half_t* Amat = Amat3 + (size_t)layer*HH*64*192;
    kG<<<dim3(1024), dim3(512), 0, stream>>>(hT, wb, wl, Amat, yT);
    kD<<<dim3(2048), dim3(256), 0, stream>>>(yT, hT, Dsk + layer*HH,
                       wgt + (size_t)layer*256*HH,
                       bglu + layer*2*HH, hT, woT, bout, out,
                       (layer == NLAYER-1) ? 1 : 0);
  }
}

// Round 17
// 251.591 us; speedup vs baseline: 1.2992x; 1.0154x over previous
//
#include <hip/hip_runtime.h>
#include <math.h>

#define BB 8
#define LL 8192
#define DD 64
#define HH 128
#define NN 64
#define NLAYER 3
#define LC 64          // chunk length
#define NC 128         // chunks per (b,h) sequence
#define LST 137        // kG local-sums f16 row stride
#define SIS 136        // kG sinit f16 [c][n2] row stride

typedef _Float16 half_t;
typedef _Float16 f16x8_t __attribute__((ext_vector_type(8)));
typedef _Float16 f16x4_t __attribute__((ext_vector_type(4)));
typedef _Float16 f16x2_t __attribute__((ext_vector_type(2)));
typedef float    f32x4_t __attribute__((ext_vector_type(4)));

// workspace sizes in float units
#define SZ_WB   ((size_t)HH*NN*2)            // 16384 (per layer)
#define SZ_WGT  ((size_t)NLAYER*256*HH/2)    // 49152 (Wglu f16 [l][g][h])
#define SZ_WOT  ((size_t)DD*HH/2)            // 4096  (WoutT f16 [d][h])
#define SZ_WIT  ((size_t)HH*DD/2)            // 4096  (WinT f16 [h][d])
#define SZ_AM   ((size_t)HH*64*192/2)        // 786432  (f16, per layer)
#define SZ_HT   ((size_t)BB*HH*LL/2)         // 4194304 (f16 [b][h][l])
#define SZ_YT   ((size_t)BB*HH*LL/2)         // 4194304 (f16 [b][h][l])

// ---------------- kPrep: fused kP2 (blocks 0-95) + kW1 (96-143) + kW2 (144-175) + kW3 (176-207) ----------------
__global__ __launch_bounds__(256) void kPrep(const float* __restrict__ logdt,
   const float* __restrict__ logA, const float* __restrict__ Aim,
   const float* __restrict__ Cre, const float* __restrict__ Cim,
   const float* __restrict__ Wglu, const float* __restrict__ Wout,
   const float* __restrict__ Win,
   float* __restrict__ wb3, float* __restrict__ wl3, half_t* __restrict__ Amat3,
   half_t* __restrict__ wgt, half_t* __restrict__ woT, half_t* __restrict__ wiT) {
  __shared__ float  ktap[4][64];
  __shared__ half_t gst[4][64][128];
  int bid = blockIdx.x;
  int t = threadIdx.x;
  if (bid < 96) {
    // ---- SSM params for all layers
    int layer = bid >> 5;
    int blk   = bid & 31;
    float* wb = wb3 + (size_t)layer*SZ_WB;
    float* wl = wl3 + (size_t)layer*SZ_WB;
    half_t* Amat = Amat3 + (size_t)layer*HH*64*192;
    int w = t >> 6;
    int n = t & 63;
    int h = blk*4 + w;
    float dt = expf(logdt[layer*HH + h]);
    int idx = (layer*HH + h)*NN + n;
    float ar = -expf(logA[idx]);
    float ai = Aim[idx];
    float er = expf(dt*ar);
    float wr = er*cosf(dt*ai), wi = er*sinf(dt*ai);   // w = exp(dt*A)
    float inv = 1.f/(ar*ar + ai*ai);
    float mr = wr - 1.f, mi = wi;                     // expm1(dtA)
    float tr = (mr*ar + mi*ai)*inv;                   // expm1(dtA)/A
    float ti = (mi*ar - mr*ai)*inv;
    float c0 = Cre[idx], c1 = Cim[idx];
    float cr = c0*tr - c1*ti, ci = c0*ti + c1*tr;     // C_eff
    wb[(h*NN+n)*2] = wr; wb[(h*NN+n)*2+1] = wi;
    float pr = 1.f, pi = 0.f;                         // w^d
    float qr = cr*wr - ci*wi, qi = cr*wi + ci*wr;     // C~ w^{d+1}
    for (int d = 0; d < 64; d++) {
      float kd = cr*pr - ci*pi;                       // Re(C~ w^d)
      kd += __shfl_xor(kd, 1);  kd += __shfl_xor(kd, 2);  kd += __shfl_xor(kd, 4);
      kd += __shfl_xor(kd, 8);  kd += __shfl_xor(kd, 16); kd += __shfl_xor(kd, 32);
      if (n == 0) ktap[w][d] = 2.f*kd;
      f16x2_t g2 = { (half_t)(2.f*qr), (half_t)(-2.f*qi) };
      *(f16x2_t*)&gst[w][d][2*n] = g2;
      float npr = pr*wr - pi*wi, npi = pr*wi + pi*wr; pr = npr; pi = npi;
      float nqr = qr*wr - qi*wi, nqi = qr*wi + qi*wr; qr = nqr; qi = nqi;
    }
    wl[(h*NN+n)*2] = pr; wl[(h*NN+n)*2+1] = pi;       // w^64
    __syncthreads();
    #pragma unroll
    for (int i = 0; i < 16; i++) {
      int idx2 = t + i*256;
      int hh = idx2 >> 10;
      int rem = idx2 & 1023;
      int l = rem >> 4, m8 = rem & 15;
      half_t* Ahh = Amat + (size_t)(blk*4 + hh)*64*192;
      *(f16x8_t*)&Ahh[(size_t)l*192 + 64 + m8*8] = *(const f16x8_t*)&gst[hh][l][m8*8];
    }
    #pragma unroll
    for (int i = 0; i < 8; i++) {
      int idx2 = t + i*256;
      int hh = idx2 >> 9;
      int rem = idx2 & 511;
      int l = rem >> 3, m8 = rem & 7;
      half_t* Ahh = Amat + (size_t)(blk*4 + hh)*64*192;
      f16x8_t v;
      #pragma unroll
      for (int j = 0; j < 8; j++) {
        int m = m8*8 + j;
        v[j] = (half_t)((m <= l) ? ktap[hh][l - m] : 0.f);
      }
      *(f16x8_t*)&Ahh[(size_t)l*192 + m8*8] = v;
    }
  } else if (bid < 144) {
    // ---- Wglu f32 -> f16 (layout preserved)
    int tid = (bid - 96)*256 + t;        // < 12288
    const float* src = Wglu + (size_t)tid*8;
    f16x8_t v;
    #pragma unroll
    for (int i = 0; i < 8; i++) v[i] = (half_t)src[i];
    *(f16x8_t*)&wgt[(size_t)tid*8] = v;
  } else if (bid < 176) {
    // ---- woT[d][h] = Wout[h][d]
    int tid = (bid - 144)*256 + t;       // < 8192
    int d = tid >> 7, h = tid & 127;
    woT[d*HH + h] = (half_t)Wout[h*DD + d];
  } else {
    // ---- wiT[h][d] = Win[d][h]
    int tid = (bid - 176)*256 + t;       // < 8192
    int h = tid >> 6, d = tid & 63;
    wiT[h*DD + d] = (half_t)Win[d*HH + h];
  }
}

// ---------------- kIn: h = x @ W_in + b_in (MFMA) -> hT f16 [b][h][l] ----------------
__global__ __launch_bounds__(256) void kIn(const float* __restrict__ x,
      const half_t* __restrict__ wiT, const float* __restrict__ bin,
      half_t* __restrict__ hT) {
  __shared__ half_t xs[64*72];
  __shared__ half_t zs[128*72];
  size_t row0 = (size_t)blockIdx.x * 64;
  int t = threadIdx.x;
  #pragma unroll
  for (int i = 0; i < 4; i++) {
    int idx = t + i*256;                  // 0..1023 float4s (64 rows x 16)
    int r = idx >> 4, c4 = idx & 15;
    float4 v = *(const float4*)&x[(row0 + r)*DD + c4*4];
    f16x4_t o = { (half_t)v.x, (half_t)v.y, (half_t)v.z, (half_t)v.w };
    *(f16x4_t*)&xs[r*72 + c4*4] = o;
  }
  __syncthreads();
  int wid = t >> 6, lane = t & 63;
  int lr = lane & 15, lq = lane >> 4, lk = lq*8;
  f32x4_t acc[4][2];
  #pragma unroll
  for (int mr = 0; mr < 4; mr++)
    #pragma unroll
    for (int nc = 0; nc < 2; nc++) {
      float bv = bin[(wid*2 + nc)*16 + lr];
      acc[mr][nc] = (f32x4_t){bv, bv, bv, bv};
    }
  #pragma unroll
  for (int ks = 0; ks < 2; ks++) {
    int k = ks*32 + lk;
    f16x8_t af[4], bf[2];
    #pragma unroll
    for (int mr = 0; mr < 4; mr++) af[mr] = *(const f16x8_t*)&xs[(mr*16 + lr)*72 + k];
    #pragma unroll
    for (int nc = 0; nc < 2; nc++)
      bf[nc] = *(const f16x8_t*)&wiT[(size_t)((wid*2 + nc)*16 + lr)*DD + k];
    #pragma unroll
    for (int mr = 0; mr < 4; mr++)
      #pragma unroll
      for (int nc = 0; nc < 2; nc++)
        acc[mr][nc] = __builtin_amdgcn_mfma_f32_16x16x32_f16(af[mr], bf[nc], acc[mr][nc], 0, 0, 0);
  }
  #pragma unroll
  for (int mr = 0; mr < 4; mr++)
    #pragma unroll
    for (int nc = 0; nc < 2; nc++) {
      int h = (wid*2 + nc)*16 + lr;
      f16x4_t v = { (half_t)acc[mr][nc][0], (half_t)acc[mr][nc][1],
                    (half_t)acc[mr][nc][2], (half_t)acc[mr][nc][3] };
      *(f16x4_t*)&zs[h*72 + mr*16 + lq*4] = v;
    }
  __syncthreads();
  size_t bb = row0 >> 13;
  int l0 = (int)(row0 & 8191);
  int h = t >> 1, hf = t & 1;
  half_t* dst = hT + ((size_t)bb*HH + h)*LL + l0 + hf*32;
  #pragma unroll
  for (int j = 0; j < 4; j++)
    *(f16x8_t*)&dst[j*8] = *(const f16x8_t*)&zs[h*72 + hf*32 + j*8];
}

// ---------------- kG: FUSED states GEMM + scan + output GEMM (512 thr, 76KB LDS) ----------------
__global__ __launch_bounds__(512) void kG(const half_t* __restrict__ hT,
      const float* __restrict__ wb, const float* __restrict__ wl,
      const half_t* __restrict__ Amat, half_t* __restrict__ yT) {
  __shared__ half_t va[128*72];          // 18432 B (V matrix; reused as y staging [c][72])
  __shared__ half_t ub[128*72];          // 18432 B
  __shared__ half_t spad[128*LST];       // 35072 B
  __shared__ float  segT[8*128];         //  4096 B
  int t = threadIdx.x;
  int h = blockIdx.x >> 3, b = blockIdx.x & 7;
  // ---- phase 0: V build + U stage
  {
    int n = t >> 3, q8 = t & 7;
    float wr = wb[(h*NN+n)*2], wi = wb[(h*NN+n)*2+1];
    float ar = wr, ai = wi;                      // -> w^8
    #pragma unroll
    for (int i = 0; i < 3; i++) { float nr = ar*ar - ai*ai, ni = 2.f*ar*ai; ar = nr; ai = ni; }
    float pr = 1.f, pi = 0.f;
    for (int e = 0; e < 7 - q8; e++) { float nr = pr*ar - pi*ai, ni = pr*ai + pi*ar; pr = nr; pi = ni; }
    int k0 = (7 - q8)*8;
    for (int i = 0; i < 8; i++) {
      int m = 63 - (k0 + i);
      va[(2*n)*72 + m]   = (half_t)pr;           // Re(w^{63-m})
      va[(2*n+1)*72 + m] = (half_t)pi;
      float nr = pr*wr - pi*wi, ni = pr*wi + pi*wr; pr = nr; pi = ni;
    }
  }
  {
    const half_t* src = hT + ((size_t)b*HH + h)*LL;
    #pragma unroll
    for (int i = 0; i < 2; i++) {
      int idx = t + i*512;
      int row = idx >> 3, off = (idx & 7)*8;
      *(f16x8_t*)&ub[row*72 + off] = *(const f16x8_t*)&src[row*64 + off];
    }
  }
  __syncthreads();
  int wid = t >> 6, lane = t & 63;
  int lr = lane & 15, lq = lane >> 4, lk = lq*8;
  // ---- phase 1: local-states GEMM, 8 waves
  {
    int wr_ = wid & 1, wc = wid >> 1;
    f32x4_t acc[4][2];
    #pragma unroll
    for (int mr = 0; mr < 4; mr++) { acc[mr][0] = (f32x4_t){0.f,0.f,0.f,0.f}; acc[mr][1] = (f32x4_t){0.f,0.f,0.f,0.f}; }
    #pragma unroll
    for (int ks = 0; ks < 2; ks++) {
      int k = ks*32 + lk;
      f16x8_t af[4], bf[2];
      #pragma unroll
      for (int mr = 0; mr < 4; mr++) af[mr] = *(const f16x8_t*)&va[(wr_*64 + mr*16 + lr)*72 + k];
      #pragma unroll
      for (int nc = 0; nc < 2; nc++) bf[nc] = *(const f16x8_t*)&ub[(wc*32 + nc*16 + lr)*72 + k];
      #pragma unroll
      for (int mr = 0; mr < 4; mr++)
        #pragma unroll
        for (int nc = 0; nc < 2; nc++)
          acc[mr][nc] = __builtin_amdgcn_mfma_f32_16x16x32_f16(af[mr], bf[nc], acc[mr][nc], 0, 0, 0);
    }
    #pragma unroll
    for (int mr = 0; mr < 4; mr++)
      #pragma unroll
      for (int nc = 0; nc < 2; nc++)
        #pragma unroll
        for (int r = 0; r < 4; r++)
          spad[(wr_*64 + mr*16 + lq*4 + r)*LST + (wc*32 + nc*16 + lr)] = (half_t)acc[mr][nc][r];
  }
  __syncthreads();
  // ---- phase 2: scan; prefixes in registers; transposed sinit write into spad
  {
    int n = t & 63, seg = t >> 6;
    int c0 = seg*16;
    float w64r = wl[(h*NN+n)*2], w64i = wl[(h*NN+n)*2+1];
    float pregr[16], pregi[16];
    float cr = 0.f, ci = 0.f;
    #pragma unroll
    for (int i = 0; i < 16; i++) {
      int c = c0 + i;
      float lre = (float)spad[(2*n)*LST + c];
      float lim = (float)spad[(2*n+1)*LST + c];
      pregr[i] = cr; pregi[i] = ci;
      float nr = fmaf(w64r, cr, fmaf(-w64i, ci, lre));
      float ni = fmaf(w64i, cr, fmaf(w64r, ci, lim));
      cr = nr; ci = ni;
    }
    segT[seg*128 + 2*n] = cr; segT[seg*128 + 2*n+1] = ci;
    __syncthreads();
    float ar = w64r, ai = w64i;           // -> w64^16
    #pragma unroll
    for (int i = 0; i < 4; i++) { float nr = ar*ar - ai*ai, ni = 2.f*ar*ai; ar = nr; ai = ni; }
    float br = 0.f, bi = 0.f;
    for (int k = 0; k < seg; k++) {
      float tr_ = segT[k*128 + 2*n], ti_ = segT[k*128 + 2*n+1];
      float nr = fmaf(ar, br, fmaf(-ai, bi, tr_));
      float ni = fmaf(ai, br, fmaf(ar, bi, ti_));
      br = nr; bi = ni;
    }
    float wpr = 1.f, wpi = 0.f;
    #pragma unroll
    for (int i = 0; i < 16; i++) {
      int c = c0 + i;
      float sr = pregr[i] + wpr*br - wpi*bi;
      float si = pregi[i] + wpr*bi + wpi*br;
      f16x2_t v = { (half_t)sr, (half_t)si };
      *(f16x2_t*)&spad[c*SIS + 2*n] = v;
      float nr = wpr*w64r - wpi*w64i, ni = wpr*w64i + wpi*w64r;
      wpr = nr; wpi = ni;
    }
  }
  __syncthreads();
  // ---- phase 3: output GEMM, 8 waves; results staged into va [c][72]
  {
    const half_t* Ag = Amat + (size_t)h*64*192;
    f32x4_t acc[4];
    #pragma unroll
    for (int mr = 0; mr < 4; mr++) acc[mr] = (f32x4_t){0.f,0.f,0.f,0.f};
    int c = wid*16 + lr;
    #pragma unroll
    for (int ks = 0; ks < 6; ks++) {
      int k = ks*32 + lk;
      f16x8_t af[4];
      #pragma unroll
      for (int mr = 0; mr < 4; mr++) af[mr] = *(const f16x8_t*)&Ag[(size_t)(mr*16 + lr)*192 + k];
      f16x8_t bf = (ks < 2) ? *(const f16x8_t*)&ub[c*72 + k]
                            : *(const f16x8_t*)&spad[c*SIS + (k - 64)];
      #pragma unroll
      for (int mr = 0; mr < 4; mr++)
        acc[mr] = __builtin_amdgcn_mfma_f32_16x16x32_f16(af[mr], bf, acc[mr], 0, 0, 0);
    }
    #pragma unroll
    for (int mr = 0; mr < 4; mr++) {
      int l0 = mr*16 + lq*4;
      f16x4_t v = { (half_t)acc[mr][0], (half_t)acc[mr][1],
                    (half_t)acc[mr][2], (half_t)acc[mr][3] };
      *(f16x4_t*)&va[c*72 + l0] = v;
    }
  }
  __syncthreads();
  // ---- coalesced yT write
  {
    half_t* yp = yT + ((size_t)b*HH + h)*LL;
    int c = t >> 2, q = t & 3;
    const half_t* src = &va[c*72 + q*16];
    f16x8_t v0 = *(const f16x8_t*)src;
    f16x8_t v1 = *(const f16x8_t*)(src + 8);
    *(f16x8_t*)&yp[c*64 + q*16]     = v0;
    *(f16x8_t*)&yp[c*64 + q*16 + 8] = v1;
  }
}

// ---------------- kD: skip+gelu+MFMA GLU+residual+rmsnorm; 3 barrier phases ----------------
// u staged to ulds f16 in stage 1; residual folded into stage-2 epilogue (bit-identical f32 add).
// Last layer fuses the out-GEMM (kE eliminated).
__global__ __launch_bounds__(256) void kD(const half_t* __restrict__ yT,
     const half_t* __restrict__ hTin, const float* __restrict__ dskip,
     const half_t* __restrict__ wgt, const float* __restrict__ bglu,
     half_t* __restrict__ hT, const half_t* __restrict__ woT,
     const float* __restrict__ bout, float* __restrict__ out, int last) {
  __shared__ half_t ylds[32][136];
  __shared__ half_t ulds[32][136];
  __shared__ float  zlds[32][133];
  __shared__ float  rnorm[32];
  size_t row0 = (size_t)blockIdx.x * 32;
  int b  = (int)(row0 >> 13);
  int l0 = (int)(row0 & 8191);
  int t = threadIdx.x;
  int h  = t >> 1, hf = t & 1;
  int lbase = hf*16;
  const half_t* yb  = yT   + ((size_t)b*HH + h)*LL + l0 + lbase;
  const half_t* ubp = hTin + ((size_t)b*HH + h)*LL + l0 + lbase;
  f16x8_t ya = *(const f16x8_t*)yb;
  f16x8_t yc = *(const f16x8_t*)(yb + 8);
  f16x8_t ua = *(const f16x8_t*)ubp;
  f16x8_t uc = *(const f16x8_t*)(ubp + 8);
  float d = dskip[h];
  #pragma unroll
  for (int i = 0; i < 8; i++) {
    float v = fmaf((float)ua[i], d, (float)ya[i]);
    float arg = 0.7978845608028654f*(v + 0.044715f*v*v*v);
    arg = fminf(fmaxf(arg, -15.f), 15.f);
    float e = __expf(2.f*arg);
    ylds[lbase + i][h] = (half_t)(0.5f*v*(1.f + (e - 1.f)/(e + 1.f)));
    ulds[lbase + i][h] = ua[i];
  }
  #pragma unroll
  for (int i = 0; i < 8; i++) {
    float v = fmaf((float)uc[i], d, (float)yc[i]);
    float arg = 0.7978845608028654f*(v + 0.044715f*v*v*v);
    arg = fminf(fmaxf(arg, -15.f), 15.f);
    float e = __expf(2.f*arg);
    ylds[lbase + 8 + i][h] = (half_t)(0.5f*v*(1.f + (e - 1.f)/(e + 1.f)));
    ulds[lbase + 8 + i][h] = uc[i];
  }
  __syncthreads();
  // ---- stage 2: MFMA GLU; epilogue adds bias, gate, residual
  {
    int w = t >> 6, lane = t & 63;
    int lr = lane & 15, lq = lane >> 4;
    f16x8_t af[2][4];
    #pragma unroll
    for (int mt = 0; mt < 2; mt++)
      #pragma unroll
      for (int ks = 0; ks < 4; ks++)
        af[mt][ks] = *(const f16x8_t*)&ylds[mt*16 + lr][ks*32 + lq*8];
    int ntl[4] = { 2*w, 2*w+1, 2*w+8, 2*w+9 };
    f32x4_t acc[2][4];
    #pragma unroll
    for (int mt = 0; mt < 2; mt++)
      #pragma unroll
      for (int p = 0; p < 4; p++) acc[mt][p] = (f32x4_t){0.f,0.f,0.f,0.f};
    #pragma unroll
    for (int p = 0; p < 4; p++) {
      int nt = ntl[p];
      #pragma unroll
      for (int ks = 0; ks < 4; ks++) {
        f16x8_t bf = *(const f16x8_t*)&wgt[(size_t)(nt*16 + lr)*HH + ks*32 + lq*8];
        #pragma unroll
        for (int mt = 0; mt < 2; mt++)
          acc[mt][p] = __builtin_amdgcn_mfma_f32_16x16x32_f16(af[mt][ks], bf, acc[mt][p], 0, 0, 0);
      }
    }
    #pragma unroll
    for (int p = 0; p < 2; p++) {
      int col = 32*w + p*16 + lr;
      float ba = bglu[col], bg = bglu[col + 128];
      #pragma unroll
      for (int mt = 0; mt < 2; mt++)
        #pragma unroll
        for (int r = 0; r < 4; r++) {
          int row = mt*16 + lq*4 + r;
          float a = acc[mt][p][r]   + ba;
          float g = acc[mt][p+2][r] + bg;
          float s = 1.f/(1.f + __expf(-g));
          zlds[row][col] = a*s + (float)ulds[row][col];
        }
    }
  }
  __syncthreads();
  // ---- stage 4: row 2-norms
  #pragma unroll
  for (int i = 0; i < 4; i++) {
    int idx = i*256 + t;
    int row = idx >> 5, c4 = idx & 31;
    const float4 f = *reinterpret_cast<const float4*>(&zlds[row][c4*4]);
    float s = fmaf(f.x, f.x, fmaf(f.y, f.y, fmaf(f.z, f.z, f.w*f.w)));
    s += __shfl_xor(s, 1); s += __shfl_xor(s, 2); s += __shfl_xor(s, 4);
    s += __shfl_xor(s, 8); s += __shfl_xor(s, 16);
    if ((t & 31) == 0) rnorm[row] = s;
  }
  __syncthreads();
  // ---- stage 5: scale; coalesced hT store / last-layer out-GEMM
  f16x8_t o0, o1;
  #pragma unroll
  for (int i = 0; i < 8; i++) {
    float sc = 11.313708498984761f / fmaxf(sqrtf(rnorm[lbase + i]), 1e-12f);
    o0[i] = (half_t)(zlds[lbase + i][h]*sc);
  }
  #pragma unroll
  for (int i = 0; i < 8; i++) {
    float sc = 11.313708498984761f / fmaxf(sqrtf(rnorm[lbase + 8 + i]), 1e-12f);
    o1[i] = (half_t)(zlds[lbase + 8 + i][h]*sc);
  }
  if (!last) {
    half_t* hb = hT + ((size_t)b*HH + h)*LL + l0 + lbase;
    *(f16x8_t*)hb = o0;
    *(f16x8_t*)(hb + 8) = o1;
  } else {
    #pragma unroll
    for (int i = 0; i < 8; i++) ylds[lbase + i][h]     = o0[i];
    #pragma unroll
    for (int i = 0; i < 8; i++) ylds[lbase + 8 + i][h] = o1[i];
    __syncthreads();
    int w = t >> 6, lane = t & 63;
    int lr = lane & 15, lq = lane >> 4;
    int dd = w*16 + lr;
    f32x4_t oacc[2];
    float bv = bout[dd];
    oacc[0] = (f32x4_t){bv, bv, bv, bv};
    oacc[1] = (f32x4_t){bv, bv, bv, bv};
    #pragma unroll
    for (int ks = 0; ks < 4; ks++) {
      int k = ks*32 + lq*8;
      f16x8_t bf = *(const f16x8_t*)&woT[(size_t)dd*HH + k];
      #pragma unroll
      for (int mt = 0; mt < 2; mt++) {
        f16x8_t af = *(const f16x8_t*)&ylds[mt*16 + lr][k];
        oacc[mt] = __builtin_amdgcn_mfma_f32_16x16x32_f16(af, bf, oacc[mt], 0, 0, 0);
      }
    }
    #pragma unroll
    for (int mt = 0; mt < 2; mt++)
      #pragma unroll
      for (int r = 0; r < 4; r++)
        out[(row0 + mt*16 + lq*4 + r)*DD + dd] = oacc[mt][r];
  }
}

extern "C" void kernel_launch(void* const* d_in, const int* in_sizes, int n_in,
                              void* d_out, int out_size, void* d_ws, size_t ws_size,
                              hipStream_t stream) {
  const float* x     = (const float*)d_in[0];
  const float* Win   = (const float*)d_in[1];
  const float* bin   = (const float*)d_in[2];
  const float* logdt = (const float*)d_in[3];
  const float* logA  = (const float*)d_in[4];
  const float* Aim   = (const float*)d_in[5];
  const float* Cre   = (const float*)d_in[6];
  const float* Cim   = (const float*)d_in[7];
  const float* Dsk   = (const float*)d_in[8];
  const float* Wglu  = (const float*)d_in[9];
  const float* bglu  = (const float*)d_in[10];
  const float* Wout  = (const float*)d_in[11];
  const float* bout  = (const float*)d_in[12];
  float* out = (float*)d_out;

  // Total ≈ 43.6 MB (safe under the proven 104.2MB bound)
  float* ws   = (float*)d_ws;
  float* wb3  = ws;                          // 3*16384
  float* wl3  = wb3 + 3*SZ_WB;               // 3*16384
  float* wgtF = wl3 + 3*SZ_WB;               // 49152
  float* woTF = wgtF + SZ_WGT;               // 4096
  float* wiTF = woTF + SZ_WOT;               // 4096
  float* amF  = wiTF + SZ_WIT;               // Amat3 f16: 3*786432 (9.4MB)
  float* htF  = amF + 3*SZ_AM;               // hT f16 (16.8MB)
  float* ytF  = htF + SZ_HT;                 // yT f16 (16.8MB)
  half_t* wgt    = (half_t*)wgtF;
  half_t* woT    = (half_t*)woTF;
  half_t* wiT    = (half_t*)wiTF;
  half_t* Amat3  = (half_t*)amF;
  half_t* hT     = (half_t*)htF;
  half_t* yT     = (half_t*)ytF;

  kPrep<<<dim3(208), dim3(256), 0, stream>>>(logdt, logA, Aim, Cre, Cim,
                                             Wglu, Wout, Win,
                                             wb3, wl3, Amat3, wgt, woT, wiT);
  kIn<<<dim3(1024), dim3(256), 0, stream>>>(x, wiT, bin, hT);

  for (int layer = 0; layer < NLAYER; ++layer) {
    const float* wb = wb3 + (size_t)layer*SZ_WB;
    const float* wl = wl3 + (size_t)layer*SZ_WB;
    const half_t* Amat = Amat3 + (size_t)layer*HH*64*192;
    kG<<<dim3(1024), dim3(512), 0, stream>>>(hT, wb, wl, Amat, yT);
    kD<<<dim3(2048), dim3(256), 0, stream>>>(yT, hT, Dsk + layer*HH,
                       wgt + (size_t)layer*256*HH,
                       bglu + layer*2*HH, hT, woT, bout, out,
                       (layer == NLAYER-1) ? 1 : 0);
  }
}